// Round 11
// baseline (8582.298 us; speedup 1.0000x reference)
//
#include <hip/hip_runtime.h>

#define FF 512
#define HH 1024
#define LL 128
#define BB 128
#define PP 1024

typedef short short8 __attribute__((ext_vector_type(8)));
typedef float floatx4 __attribute__((ext_vector_type(4)));
typedef unsigned short ushort_t;
typedef unsigned long long u64;

__device__ __forceinline__ float sigm(float x) {
    return 1.0f / (1.0f + __expf(-x));
}
// overflow-safe tanh: exp(-2|x|) underflows to 0 for large |x| -> +-1
__device__ __forceinline__ float tanh_fast(float x) {
    float ax = fabsf(x);
    float e = __expf(-2.0f * ax);
    float r = (1.0f - e) / (1.0f + e);
    return copysignf(r, x);
}

__device__ __forceinline__ unsigned short bf16_rtne(float x) {
    unsigned int u = __float_as_uint(x);
    return (unsigned short)((u + 0x7FFFu + ((u >> 16) & 1u)) >> 16);
}
__device__ __forceinline__ void split_bf16(float x, unsigned short& hi, unsigned short& lo) {
    hi = bf16_rtne(x);
    float hf = __uint_as_float(((unsigned int)hi) << 16);
    lo = bf16_rtne(x - hf);
}

// --- agent-scope h exchange: coherent across XCDs (verified R3/R4/R8/R9) ---
__device__ __forceinline__ int4 ld_h16(const ushort_t* p) {
    u64* q = (u64*)p;
    u64 a = __hip_atomic_load(q,     __ATOMIC_RELAXED, __HIP_MEMORY_SCOPE_AGENT);
    u64 b = __hip_atomic_load(q + 1, __ATOMIC_RELAXED, __HIP_MEMORY_SCOPE_AGENT);
    return make_int4((int)(unsigned)(a & 0xffffffffull), (int)(unsigned)(a >> 32),
                     (int)(unsigned)(b & 0xffffffffull), (int)(unsigned)(b >> 32));
}
__device__ __forceinline__ void st_h8(ushort_t* p, uint2 v) {
    u64 x = ((u64)v.y << 32) | (u64)v.x;
    __hip_atomic_store((u64*)p, x, __ATOMIC_RELAXED, __HIP_MEMORY_SCOPE_AGENT);
}
__device__ __forceinline__ float4 ld_f4_bypass(const float* p) {
    u64* q = (u64*)p;
    u64 a = __hip_atomic_load(q,     __ATOMIC_RELAXED, __HIP_MEMORY_SCOPE_AGENT);
    u64 b = __hip_atomic_load(q + 1, __ATOMIC_RELAXED, __HIP_MEMORY_SCOPE_AGENT);
    float4 r;
    ((u64*)&r)[0] = a;
    ((u64*)&r)[1] = b;
    return r;
}

// monotonic-counter grid barrier (VERIFIED R3/R4/R8/R9)
__device__ __forceinline__ void grid_barrier(unsigned* cnt, unsigned target, int tid) {
    __syncthreads();
    if (tid == 0) {
        __hip_atomic_fetch_add(cnt, 1u, __ATOMIC_RELAXED, __HIP_MEMORY_SCOPE_AGENT);
        while (__hip_atomic_load(cnt, __ATOMIC_RELAXED, __HIP_MEMORY_SCOPE_AGENT) < target) {
            __builtin_amdgcn_s_sleep(2);
        }
    }
    __syncthreads();
}

__global__ void fillz(float* p, int n) {
    int i = blockIdx.x * blockDim.x + threadIdx.x;
    if (i < n) p[i] = 0.0f;
}

// fp32 [n] -> bf16 (RTNE) [n]
__global__ void round_w(const float* __restrict__ W, ushort_t* __restrict__ hi, int n) {
    int i = blockIdx.x * blockDim.x + threadIdx.x;
    if (i < n) hi[i] = bf16_rtne(W[i]);
}

// ---------------------------------------------------------------------------
// Persistent cooperative encoder, v8 (halved h-multicast):
// R9 falsified the FETCH law (FETCH -27%, time flat): the binding resource
// is the agent-atomic h-read multicast (64 MB/step @ ~2.7 TB/s ~= 24us).
// Multicast factor = #column-groups = 32. Re-tile: 32f x 256 outcols per
// block (16 row-groups x 16 col-groups, grid 256) -> each h element read by
// 16 blocks, h traffic 32 MB/step. W per block = 256 rows streamed; XCD
// decode c=id&15 puts col-groups {xcd, xcd+8} on one XCD (W slice 1 MB/L2).
// Waves = (gate g, n-half nh): 32x32 tile, full-serial K (R9's verified
// accumulation order -> identical absmax). A-tile 8KB/chunk, 1 int4/thread
// staging, rotate swizzle. Protocol (agent atomics, counter barrier,
// epilogue st_h8) byte-for-byte verified code. Static 36 KB LDS.
// ---------------------------------------------------------------------------
__global__ __launch_bounds__(512, 1) void lstm_encoder_persistent(
    ushort_t* __restrict__ hhiA, ushort_t* __restrict__ hloA,   // buf0 (zeroed)
    ushort_t* __restrict__ hhiB, ushort_t* __restrict__ hloB,   // buf1
    float* __restrict__ h_fin,   // fp32 final h   (h_a)
    float* __restrict__ c_fin,   // fp32 final c   (c_st)
    const ushort_t* __restrict__ Whi1,
    const ushort_t* __restrict__ Whi2,
    const float* __restrict__ emb1, const float* __restrict__ emb2,
    const int* __restrict__ tok1, const int* __restrict__ len1,
    const int* __restrict__ tok2, const int* __restrict__ len2,
    unsigned* __restrict__ barCnt)
{
    // A dbuf during K-loop: parity p at [p*8192, +8192): hi @+0 (4KB), lo @+4096.
    // Gx after loop (aliases A): [0, 34816) = 4 gates x 32 rows x 68 fp32.
    __shared__ __align__(16) char smem[36864];
    float* Gx = (float*)smem;

    const int tid = threadIdx.x;
    const int w = tid >> 6;              // wave 0..7
    const int l = tid & 63;
    const int q = l >> 4;                // k-quad 0..3
    const int fr = l & 15;               // fragment row/col
    const int g = w & 3;                 // gate
    const int nh = w >> 2;               // n-half 0/1 (32 cols each)

    // decode: col-group c = id&15 (XCD xcd=id&7 gets c in {xcd, xcd+8}),
    // row-group r = id>>4.
    const int id = blockIdx.x;
    const int cg = id & 15;
    const int rg = id >> 4;
    const int fbase = rg * 32;
    const int n0 = cg * 64;

    // --- A staging: 512 thr x 1 int4; sgrp 0=hi 1=lo ---
    const int sgrp = tid >> 8;
    const int u = tid & 255;
    const int arow = u >> 3;             // 0..31
    const int s0 = u & 7;                // slot 0..7
    const size_t a_goff = (size_t)(fbase + arow) * HH + s0 * 8;
    const int ldsIdx = arow * 8 + ((s0 + arow) & 7);
    const int aoff = sgrp * 4096;        // hi/lo sub-region

    // --- B fragment offsets (W-base-independent), subtiles n=0,1 ---
    const size_t brow0 = ((size_t)g * HH + n0 + nh * 32 + 0 * 16 + fr) * HH + q * 8;
    const size_t brow1 = ((size_t)g * HH + n0 + nh * 32 + 1 * 16 + fr) * HH + q * 8;

    // --- epilogue map + persistent cell state: (row rr, 4 cols at c0) ---
    const int rr = tid >> 4;             // 0..31
    const int c0 = (tid & 15) * 4;       // 0..60
    const int f = fbase + rr;
    const int gc = n0 + c0;
    const size_t gidx = (size_t)f * HH + gc;
    float4 creg = make_float4(0.f, 0.f, 0.f, 0.f);
    float4 hreg = make_float4(0.f, 0.f, 0.f, 0.f);

    // B double buffer [parity][n][kk]; prefetch chunk0 of t=0
    short8 Bs[2][2][2];
    #pragma unroll
    for (int kk = 0; kk < 2; ++kk) {
        Bs[0][0][kk] = *(const short8*)(Whi1 + brow0 + kk * 32);
        Bs[0][1][kk] = *(const short8*)(Whi1 + brow1 + kk * 32);
    }

    for (int t = 0; t < 256; ++t) {
        const int tt = t & 127;
        const bool ph2 = t >= 128;
        const ushort_t* Wh = ph2 ? Whi2 : Whi1;
        const ushort_t* WhN = (t >= 127) ? Whi2 : Whi1;  // base for t+1
        const float* emb = ph2 ? emb2 : emb1;
        const int* tok = ph2 ? tok2 : tok1;
        const int* len = ph2 ? len2 : len1;
        const ushort_t* rhh = (t & 1) ? hhiB : hhiA;
        const ushort_t* rhl = (t & 1) ? hloB : hloA;
        ushort_t* whh = (t & 1) ? hhiA : hhiB;
        ushort_t* whl = (t & 1) ? hloA : hloB;
        const ushort_t* asrc = sgrp ? rhl : rhh;

        // A chunk 0 -> LDS parity 0
        {
            int4 v = ld_h16(asrc + a_goff);
            *(int4*)(smem + aoff + ldsIdx * 16) = v;
        }
        __syncthreads();

        floatx4 acc[2][2];
        #pragma unroll
        for (int m = 0; m < 2; ++m)
            #pragma unroll
            for (int n = 0; n < 2; ++n) acc[m][n] = (floatx4)(0.0f);

        int4 pa;
        #pragma unroll 2
        for (int i = 0; i < 16; ++i) {
            const int cur = i & 1, nxt = cur ^ 1;
            const char* AsH = smem + cur * 8192;
            const char* AsL = AsH + 4096;

            // A prefetch for chunk i+1 (reg; LDS-write after compute)
            if (i < 15) {
                pa = ld_h16(asrc + a_goff + (i + 1) * 64);
            }
            // B prefetch: chunks 1..15, or chunk0 of NEXT step at i==15
            {
                const ushort_t* Bp = (i < 15) ? Wh : WhN;
                const int k0 = (i < 15) ? (i + 1) * 64 : 0;
                #pragma unroll
                for (int kk = 0; kk < 2; ++kk) {
                    Bs[nxt][0][kk] = *(const short8*)(Bp + brow0 + k0 + kk * 32);
                    Bs[nxt][1][kk] = *(const short8*)(Bp + brow1 + k0 + kk * 32);
                }
            }

            // compute chunk i: 2-term (h_hi + h_lo) x W, 16 MFMA/wave
            #pragma unroll
            for (int m = 0; m < 2; ++m) {
                const int r = m * 16 + fr;
                short8 ah0 = *(const short8*)(AsH + (r * 8 + ((0 + q + r) & 7)) * 16);
                short8 ah1 = *(const short8*)(AsH + (r * 8 + ((4 + q + r) & 7)) * 16);
                short8 al0 = *(const short8*)(AsL + (r * 8 + ((0 + q + r) & 7)) * 16);
                short8 al1 = *(const short8*)(AsL + (r * 8 + ((4 + q + r) & 7)) * 16);
                #pragma unroll
                for (int n = 0; n < 2; ++n) {
                    acc[m][n] = __builtin_amdgcn_mfma_f32_16x16x32_bf16(ah0, Bs[cur][n][0], acc[m][n], 0, 0, 0);
                    acc[m][n] = __builtin_amdgcn_mfma_f32_16x16x32_bf16(al0, Bs[cur][n][0], acc[m][n], 0, 0, 0);
                    acc[m][n] = __builtin_amdgcn_mfma_f32_16x16x32_bf16(ah1, Bs[cur][n][1], acc[m][n], 0, 0, 0);
                    acc[m][n] = __builtin_amdgcn_mfma_f32_16x16x32_bf16(al1, Bs[cur][n][1], acc[m][n], 0, 0, 0);
                }
            }

            if (i < 15) {
                *(int4*)(smem + nxt * 8192 + aoff + ldsIdx * 16) = pa;
            }
            __syncthreads();
        }

        // --- Gx write (full-K per wave; C/D: col=fr, row=q*4+reg). ---
        // Gx[gate][row 0..31][col 0..63], stride 68 (pad 4). Aliases dead A.
        #pragma unroll
        for (int m = 0; m < 2; ++m)
            #pragma unroll
            for (int n = 0; n < 2; ++n)
                #pragma unroll
                for (int r4 = 0; r4 < 4; ++r4)
                    Gx[g * 2176 + (m * 16 + q * 4 + r4) * 68 + nh * 32 + n * 16 + fr] = acc[m][n][r4];
        __syncthreads();

        // --- fused cell update; c and mask-h in registers ---
        const float* ib = emb + (size_t)tok[f * LL + tt] * 4096;
        const bool upd = tt < len[f];

        float4 gv[4];
        #pragma unroll
        for (int gg = 0; gg < 4; ++gg) {
            gv[gg] = *(const float4*)&Gx[gg * 2176 + rr * 68 + c0];
            const float4 ibv = ld_f4_bypass(ib + gg * 1024 + gc);
            gv[gg].x += ibv.x; gv[gg].y += ibv.y; gv[gg].z += ibv.z; gv[gg].w += ibv.w;
        }

        unsigned short hb[4], lb[4];
        {
            const float* gi = (const float*)&gv[0];
            const float* gf = (const float*)&gv[1];
            const float* gn = (const float*)&gv[2];
            const float* go = (const float*)&gv[3];
            float* cr = (float*)&creg;
            float* hr = (float*)&hreg;
            #pragma unroll
            for (int j = 0; j < 4; ++j) {
                float cn = sigm(gf[j]) * cr[j] + sigm(gi[j]) * tanh_fast(gn[j]);
                float hn = sigm(go[j]) * tanh_fast(cn);
                if (upd) { cr[j] = cn; hr[j] = hn; }
                split_bf16(hr[j], hb[j], lb[j]);
            }
        }
        uint2 hp, lp;
        hp.x = (unsigned)hb[0] | ((unsigned)hb[1] << 16);
        hp.y = (unsigned)hb[2] | ((unsigned)hb[3] << 16);
        lp.x = (unsigned)lb[0] | ((unsigned)lb[1] << 16);
        lp.y = (unsigned)lb[2] | ((unsigned)lb[3] << 16);
        st_h8(whh + gidx, hp);
        st_h8(whl + gidx, lp);
        if (t == 255) {
            *(float4*)(h_fin + gidx) = hreg;
            *(float4*)(c_fin + gidx) = creg;
        }
        grid_barrier(barCnt, 256u * (unsigned)(t + 1), tid);
    }
}

// ---------------------------------------------------------------------------
// bf16-split MFMA LSTM step (2-term) — used by the 16 decoder steps
// (initE = u_p, tokens/lengths = null). Unchanged from R8 (verified).
// ---------------------------------------------------------------------------
__global__ __launch_bounds__(512, 2) void lstm_step_mfma(
    const float* __restrict__ h_in,
    const ushort_t* __restrict__ hhi,
    const ushort_t* __restrict__ hlo,
    float* __restrict__ h_out,
    ushort_t* __restrict__ hhi_o,
    ushort_t* __restrict__ hlo_o,
    float* __restrict__ c_st,
    const ushort_t* __restrict__ Whi,
    const float* __restrict__ initE,
    const int* __restrict__ tokens,
    const int* __restrict__ lengths,
    int t)
{
    __shared__ __align__(16) char smem[65536];
    float* Gx = (float*)smem;

    const int tid = threadIdx.x;
    const int w = tid >> 6;
    const int g = w & 3;
    const int kh = w >> 2;
    const int l = tid & 63;
    const int q = l >> 4;
    const int fr = l & 15;

    const int id = blockIdx.x;
    const int by = (id & 7) + 8 * ((id >> 3) & 3);
    const int bx = id >> 5;
    const int fbase = bx * 64;
    const int n0 = by * 32;

    const int sgrp = tid >> 8;
    const int u = tid & 255;
    const int ar = u >> 2;
    const int s0 = u & 3;
    const size_t a_goff = (size_t)(fbase + ar) * HH + s0 * 8 + sgrp * 512;
    const int sw0 = (s0 + ar) & 7;
    const int sw1 = ((s0 + 4) + ar) & 7;
    const int lds0 = ar * 8 + sw0;
    const int lds1 = ar * 8 + sw1;

    const size_t brow0 = ((size_t)(g * HH) + n0 + fr) * HH + q * 8 + kh * 512;
    const size_t brow1 = ((size_t)(g * HH) + n0 + 16 + fr) * HH + q * 8 + kh * 512;

    floatx4 acc[4][2];
    #pragma unroll
    for (int m = 0; m < 4; ++m)
        #pragma unroll
        for (int n = 0; n < 2; ++n) acc[m][n] = (floatx4)(0.0f);

    int4 pa_h0 = *(const int4*)(hhi + a_goff);
    int4 pa_h1 = *(const int4*)(hhi + a_goff + 32);
    int4 pa_l0 = *(const int4*)(hlo + a_goff);
    int4 pa_l1 = *(const int4*)(hlo + a_goff + 32);

    short8 Bh[2][2][2];
    #pragma unroll
    for (int kk = 0; kk < 2; ++kk) {
        Bh[0][0][kk] = *(const short8*)(Whi + brow0 + kk * 32);
        Bh[0][1][kk] = *(const short8*)(Whi + brow1 + kk * 32);
    }

    {
        char* R0 = smem + sgrp * 32768;
        ((int4*)R0)[lds0] = pa_h0;
        ((int4*)R0)[lds1] = pa_h1;
        ((int4*)(R0 + 8192))[lds0] = pa_l0;
        ((int4*)(R0 + 8192))[lds1] = pa_l1;
    }
    __syncthreads();

    #pragma unroll 2
    for (int i = 0; i < 8; ++i) {
        const int cur = i & 1, nxt = cur ^ 1;
        const char* AsH = smem + (kh * 2 + cur) * 16384;
        const char* AsL = AsH + 8192;

        if (i < 7) {
            const int k0 = (i + 1) * 64;
            pa_h0 = *(const int4*)(hhi + a_goff + k0);
            pa_h1 = *(const int4*)(hhi + a_goff + k0 + 32);
            pa_l0 = *(const int4*)(hlo + a_goff + k0);
            pa_l1 = *(const int4*)(hlo + a_goff + k0 + 32);
            #pragma unroll
            for (int kk = 0; kk < 2; ++kk) {
                Bh[nxt][0][kk] = *(const short8*)(Whi + brow0 + k0 + kk * 32);
                Bh[nxt][1][kk] = *(const short8*)(Whi + brow1 + k0 + kk * 32);
            }
        }

        #pragma unroll
        for (int m = 0; m < 4; ++m) {
            const int r = m * 16 + fr;
            short8 ah0 = *(const short8*)(AsH + (r * 8 + ((0 + q + r) & 7)) * 16);
            short8 ah1 = *(const short8*)(AsH + (r * 8 + ((4 + q + r) & 7)) * 16);
            short8 al0 = *(const short8*)(AsL + (r * 8 + ((0 + q + r) & 7)) * 16);
            short8 al1 = *(const short8*)(AsL + (r * 8 + ((4 + q + r) & 7)) * 16);
            #pragma unroll
            for (int n = 0; n < 2; ++n) {
                acc[m][n] = __builtin_amdgcn_mfma_f32_16x16x32_bf16(ah0, Bh[cur][n][0], acc[m][n], 0, 0, 0);
                acc[m][n] = __builtin_amdgcn_mfma_f32_16x16x32_bf16(al0, Bh[cur][n][0], acc[m][n], 0, 0, 0);
                acc[m][n] = __builtin_amdgcn_mfma_f32_16x16x32_bf16(ah1, Bh[cur][n][1], acc[m][n], 0, 0, 0);
                acc[m][n] = __builtin_amdgcn_mfma_f32_16x16x32_bf16(al1, Bh[cur][n][1], acc[m][n], 0, 0, 0);
            }
        }

        if (i < 7) {
            char* DH = smem + (sgrp * 2 + nxt) * 16384;
            ((int4*)DH)[lds0] = pa_h0;
            ((int4*)DH)[lds1] = pa_h1;
            ((int4*)(DH + 8192))[lds0] = pa_l0;
            ((int4*)(DH + 8192))[lds1] = pa_l1;
        }
        __syncthreads();
    }

    if (kh == 1) {
        #pragma unroll
        for (int m = 0; m < 4; ++m)
            #pragma unroll
            for (int n = 0; n < 2; ++n)
                #pragma unroll
                for (int r = 0; r < 4; ++r)
                    Gx[(g * 64 + m * 16 + q * 4 + r) * 36 + n * 16 + fr] = acc[m][n][r];
    }
    __syncthreads();
    if (kh == 0) {
        #pragma unroll
        for (int m = 0; m < 4; ++m)
            #pragma unroll
            for (int n = 0; n < 2; ++n)
                #pragma unroll
                for (int r = 0; r < 4; ++r) {
                    const int idx = (g * 64 + m * 16 + q * 4 + r) * 36 + n * 16 + fr;
                    Gx[idx] += acc[m][n][r];
                }
    }
    __syncthreads();

    const int rr = tid >> 3;
    const int c0 = (tid & 7) * 4;
    const int f = fbase + rr;
    const int gc = n0 + c0;
    const size_t gidx = (size_t)f * HH + gc;
    const float* ib = tokens ? (initE + (size_t)tokens[f * LL + t] * 4096)
                             : (initE + (size_t)f * 4096);
    const bool upd = lengths ? (t < lengths[f]) : true;

    float4 gv[4];
    #pragma unroll
    for (int gg = 0; gg < 4; ++gg) {
        gv[gg] = *(const float4*)&Gx[(gg * 64 + rr) * 36 + c0];
        const float4 ibv = *(const float4*)(ib + gg * 1024 + gc);
        gv[gg].x += ibv.x; gv[gg].y += ibv.y; gv[gg].z += ibv.z; gv[gg].w += ibv.w;
    }
    const float4 coldv = *(const float4*)(c_st + gidx);
    const float4 holdv = *(const float4*)(h_in + gidx);

    float4 cw, hw;
    unsigned short hb[4], lb[4];
    {
        const float* gi = (const float*)&gv[0];
        const float* gf = (const float*)&gv[1];
        const float* gn = (const float*)&gv[2];
        const float* go = (const float*)&gv[3];
        const float* co = (const float*)&coldv;
        const float* ho = (const float*)&holdv;
        #pragma unroll
        for (int j = 0; j < 4; ++j) {
            float cn = sigm(gf[j]) * co[j] + sigm(gi[j]) * tanh_fast(gn[j]);
            float hn = sigm(go[j]) * tanh_fast(cn);
            float cv = upd ? cn : co[j];
            float hv = upd ? hn : ho[j];
            ((float*)&cw)[j] = cv;
            ((float*)&hw)[j] = hv;
            split_bf16(hv, hb[j], lb[j]);
        }
    }
    *(float4*)(c_st + gidx) = cw;
    *(float4*)(h_out + gidx) = hw;
    uint2 hp, lp;
    hp.x = (unsigned)hb[0] | ((unsigned)hb[1] << 16);
    hp.y = (unsigned)hb[2] | ((unsigned)hb[3] << 16);
    lp.x = (unsigned)lb[0] | ((unsigned)lb[1] << 16);
    lp.y = (unsigned)lb[2] | ((unsigned)lb[3] << 16);
    *(uint2*)(hhi_o + gidx) = hp;
    *(uint2*)(hlo_o + gidx) = lp;
}

// ---------------------------------------------------------------------------
// Generic fp32 C[M][N] = A[M][K] @ W[N][K]^T + bias[N]
// grid (M/32, N/64), block 256; per thread 4x2.
// ---------------------------------------------------------------------------
__global__ __launch_bounds__(256) void gemm_bias(
    const float* __restrict__ A, const float* __restrict__ W,
    const float* __restrict__ bias, float* __restrict__ C,
    int N, int K)
{
    __shared__ __align__(16) float As[16][32];
    __shared__ __align__(16) float Bs[16][64];
    const int tid = threadIdx.x;
    const int tm = tid & 7;
    const int tn = tid >> 3;
    const int m0 = blockIdx.x * 32, n0 = blockIdx.y * 64;
    const int am = tid >> 3;
    const int ak = (tid & 7) * 2;
    const int br = tid >> 2;
    const int bk = (tid & 3) * 4;
    const float* arow = A + (size_t)(m0 + am) * K;
    const float* brow = W + (size_t)(n0 + br) * K;
    float acc[4][2] = {};
    const int tm4 = tm * 4, tn2 = tn * 2;

    for (int k0 = 0; k0 < K; k0 += 16) {
        __syncthreads();
        float2 av = *(const float2*)(arow + k0 + ak);
        float4 bv = *(const float4*)(brow + k0 + bk);
        As[ak][am] = av.x; As[ak + 1][am] = av.y;
        Bs[bk][br] = bv.x; Bs[bk + 1][br] = bv.y;
        Bs[bk + 2][br] = bv.z; Bs[bk + 3][br] = bv.w;
        __syncthreads();
        #pragma unroll
        for (int k = 0; k < 16; ++k) {
            float4 a = *(const float4*)&As[k][tm4];
            float2 b = *(const float2*)&Bs[k][tn2];
            acc[0][0] += a.x * b.x; acc[0][1] += a.x * b.y;
            acc[1][0] += a.y * b.x; acc[1][1] += a.y * b.y;
            acc[2][0] += a.z * b.x; acc[2][1] += a.z * b.y;
            acc[3][0] += a.w * b.x; acc[3][1] += a.w * b.y;
        }
    }
    float b0 = bias[n0 + tn2], b1 = bias[n0 + tn2 + 1];
    #pragma unroll
    for (int mi = 0; mi < 4; ++mi) {
        float2 o;
        o.x = acc[mi][0] + b0;
        o.y = acc[mi][1] + b1;
        *(float2*)(C + (size_t)(m0 + tm4 + mi) * N + n0 + tn2) = o;
    }
}

// ---------------------------------------------------------------------------
// pooled[b][n] = tanh(max_e (h[4b+e] @ W_mp^T) + b_mp)   (tanh monotone)
// ---------------------------------------------------------------------------
__global__ __launch_bounds__(256) void mp_pool(
    const float* __restrict__ h, const float* __restrict__ Wmp,
    const float* __restrict__ bmp, float* __restrict__ pooled)
{
    __shared__ __align__(16) float As[16][32];
    __shared__ __align__(16) float Bs[16][64];
    const int tid = threadIdx.x;
    const int tm = tid & 7;
    const int tn = tid >> 3;
    const int m0 = blockIdx.x * 32, n0 = blockIdx.y * 64;
    const int am = tid >> 3;
    const int ak = (tid & 7) * 2;
    const int br = tid >> 2;
    const int bk = (tid & 3) * 4;
    const float* arow = h + (size_t)(m0 + am) * HH;
    const float* brow = Wmp + (size_t)(n0 + br) * HH;
    float acc[4][2] = {};
    const int tm4 = tm * 4, tn2 = tn * 2;

    for (int k0 = 0; k0 < HH; k0 += 16) {
        __syncthreads();
        float2 av = *(const float2*)(arow + k0 + ak);
        float4 bv = *(const float4*)(brow + k0 + bk);
        As[ak][am] = av.x; As[ak + 1][am] = av.y;
        Bs[bk][br] = bv.x; Bs[bk + 1][br] = bv.y;
        Bs[bk + 2][br] = bv.z; Bs[bk + 3][br] = bv.w;
        __syncthreads();
        #pragma unroll
        for (int k = 0; k < 16; ++k) {
            float4 a = *(const float4*)&As[k][tm4];
            float2 b = *(const float2*)&Bs[k][tn2];
            acc[0][0] += a.x * b.x; acc[0][1] += a.x * b.y;
            acc[1][0] += a.y * b.x; acc[1][1] += a.y * b.y;
            acc[2][0] += a.z * b.x; acc[2][1] += a.z * b.y;
            acc[3][0] += a.w * b.x; acc[3][1] += a.w * b.y;
        }
    }
    float mx0 = fmaxf(fmaxf(acc[0][0], acc[1][0]), fmaxf(acc[2][0], acc[3][0]));
    float mx1 = fmaxf(fmaxf(acc[0][1], acc[1][1]), fmaxf(acc[2][1], acc[3][1]));
    mx0 += bmp[n0 + tn2];
    mx1 += bmp[n0 + tn2 + 1];
    float2 o;
    o.x = tanh_fast(mx0);
    o.y = tanh_fast(mx1);
    const int bidx = (m0 >> 2) + tm;
    *(float2*)(pooled + (size_t)bidx * HH + n0 + tn2) = o;
}

extern "C" void kernel_launch(void* const* d_in, const int* in_sizes, int n_in,
                              void* d_out, int out_size, void* d_ws, size_t ws_size,
                              hipStream_t stream)
{
    const int*   tokens_in   = (const int*)d_in[0];
    const int*   lengths_in  = (const int*)d_in[1];
    const int*   tokens_out  = (const int*)d_in[2];
    const int*   lengths_out = (const int*)d_in[3];
    const float* embedding   = (const float*)d_in[4];
    const float* W_ih_in     = (const float*)d_in[5];
    const float* W_hh_in     = (const float*)d_in[6];
    const float* b_in        = (const float*)d_in[7];
    const float* W_ih_out    = (const float*)d_in[8];
    const float* W_hh_out    = (const float*)d_in[9];
    const float* b_out       = (const float*)d_in[10];
    const float* W_ih_p      = (const float*)d_in[11];
    const float* W_hh_p      = (const float*)d_in[12];
    const float* b_p         = (const float*)d_in[13];
    const float* W_mp        = (const float*)d_in[14];
    const float* b_mp        = (const float*)d_in[15];
    const float* W_sm        = (const float*)d_in[16];
    const float* b_sm        = (const float*)d_in[17];
    float* out = (float*)d_out;

    // workspace layout (float units); total ~18.5M floats = 74 MB
    float* ws = (float*)d_ws;
    float* h_a      = ws;                  // 524288
    float* h_b      = ws + 524288;         // 524288
    float* c_st     = ws + 1048576;        // 524288
    float* embW_in  = ws + 1572864;        // 524288
    float* embW_out = ws + 2097152;        // 524288
    float* u_p      = ws + 2621440;        // 2097152
    float* pooled   = ws + 4718592;        // 131072
    ushort_t* hhi_a = (ushort_t*)(ws + 4849664);   // 524288 bf16
    ushort_t* hlo_a = (ushort_t*)(ws + 5111808);
    ushort_t* hhi_b = (ushort_t*)(ws + 5373952);
    ushort_t* hlo_b = (ushort_t*)(ws + 5636096);
    ushort_t* Whi_in  = (ushort_t*)(ws + 5898240); // 4194304 bf16 each
    ushort_t* Whi_out = (ushort_t*)(ws + 10092544);
    ushort_t* Whi_p   = (ushort_t*)(ws + 14286848);
    // barrier counter (verified single counter) at u_p[0]
    unsigned* barCnt  = (unsigned*)u_p;

    // zero h0's bf16 hi/lo (hhi_a/hlo_a adjacent) + all barrier state
    fillz<<<2048, 256, 0, stream>>>(ws + 4849664, 524288);
    fillz<<<8, 256, 0, stream>>>(u_p, 2048);

    // round the three recurrent weight matrices to bf16 (hi only; 2-term)
    round_w<<<16384, 256, 0, stream>>>(W_hh_in,  Whi_in,  4194304);
    round_w<<<16384, 256, 0, stream>>>(W_hh_out, Whi_out, 4194304);
    round_w<<<16384, 256, 0, stream>>>(W_hh_p,   Whi_p,   4194304);

    // embW = embedding @ W_ih^T + b  (x @ W_ih collapses to a gather)
    gemm_bias<<<dim3(4, 64), 256, 0, stream>>>(embedding, W_ih_in, b_in, embW_in, 4096, 128);
    gemm_bias<<<dim3(4, 64), 256, 0, stream>>>(embedding, W_ih_out, b_out, embW_out, 4096, 128);

    // --- persistent cooperative encoder: both 128-step phases, one launch ---
    {
        void* kargs[] = {
            (void*)&hhi_a, (void*)&hlo_a, (void*)&hhi_b, (void*)&hlo_b,
            (void*)&h_a, (void*)&c_st,
            (void*)&Whi_in, (void*)&Whi_out,
            (void*)&embW_in, (void*)&embW_out,
            (void*)&tokens_in, (void*)&lengths_in,
            (void*)&tokens_out, (void*)&lengths_out,
            (void*)&barCnt
        };
        hipLaunchCooperativeKernel((void*)lstm_encoder_persistent,
                                   dim3(256), dim3(512), kargs, 0, stream);
    }

    // decoder handoff: final h in h_a (fp32) + hhi_a/hlo_a (bf16), c in c_st
    float* hc = h_a;  ushort_t* hic = hhi_a;  ushort_t* loc = hlo_a;
    float* hn = h_b;  ushort_t* hin = hhi_b;  ushort_t* lon = hlo_b;

    // u_p = prev_h @ W_ih_p^T + b_p  (prev_h constant across all 16 steps)
    gemm_bias<<<dim3(16, 64), 256, 0, stream>>>(hc, W_ih_p, b_p, u_p, 4096, 1024);

    for (int t = 0; t < 16; ++t) {
        lstm_step_mfma<<<256, 512, 0, stream>>>(
            hc, hic, loc, hn, hin, lon, c_st, Whi_p, u_p,
            nullptr, nullptr, t);
        mp_pool<<<dim3(16, 16), 256, 0, stream>>>(hn, W_mp, b_mp, pooled);
        gemm_bias<<<dim3(4, 16), 256, 0, stream>>>(pooled, W_sm, b_sm,
                                                   out + (size_t)t * (BB * PP), 1024, 1024);
        float* tf = hc; hc = hn; hn = tf;
        ushort_t* th = hic; hic = hin; hin = th;
        ushort_t* tl = loc; loc = lon; lon = tl;
    }
}

// Round 12
// 7148.497 us; speedup vs baseline: 1.2006x; 1.2006x over previous
//
#include <hip/hip_runtime.h>

#define FF 512
#define HH 1024
#define LL 128
#define BB 128
#define PP 1024

typedef short short8 __attribute__((ext_vector_type(8)));
typedef float floatx4 __attribute__((ext_vector_type(4)));
typedef unsigned short ushort_t;
typedef unsigned long long u64;

__device__ __forceinline__ float sigm(float x) {
    return 1.0f / (1.0f + __expf(-x));
}
// overflow-safe tanh: exp(-2|x|) underflows to 0 for large |x| -> +-1
__device__ __forceinline__ float tanh_fast(float x) {
    float ax = fabsf(x);
    float e = __expf(-2.0f * ax);
    float r = (1.0f - e) / (1.0f + e);
    return copysignf(r, x);
}

__device__ __forceinline__ unsigned short bf16_rtne(float x) {
    unsigned int u = __float_as_uint(x);
    return (unsigned short)((u + 0x7FFFu + ((u >> 16) & 1u)) >> 16);
}
__device__ __forceinline__ void split_bf16(float x, unsigned short& hi, unsigned short& lo) {
    hi = bf16_rtne(x);
    float hf = __uint_as_float(((unsigned int)hi) << 16);
    lo = bf16_rtne(x - hf);
}

// --- agent-scope h exchange: coherent across XCDs (verified R3/R4/R8) ---
__device__ __forceinline__ int4 ld_h16(const ushort_t* p) {
    u64* q = (u64*)p;
    u64 a = __hip_atomic_load(q,     __ATOMIC_RELAXED, __HIP_MEMORY_SCOPE_AGENT);
    u64 b = __hip_atomic_load(q + 1, __ATOMIC_RELAXED, __HIP_MEMORY_SCOPE_AGENT);
    return make_int4((int)(unsigned)(a & 0xffffffffull), (int)(unsigned)(a >> 32),
                     (int)(unsigned)(b & 0xffffffffull), (int)(unsigned)(b >> 32));
}
__device__ __forceinline__ void st_h8(ushort_t* p, uint2 v) {
    u64 x = ((u64)v.y << 32) | (u64)v.x;
    __hip_atomic_store((u64*)p, x, __ATOMIC_RELAXED, __HIP_MEMORY_SCOPE_AGENT);
}
__device__ __forceinline__ float4 ld_f4_bypass(const float* p) {
    u64* q = (u64*)p;
    u64 a = __hip_atomic_load(q,     __ATOMIC_RELAXED, __HIP_MEMORY_SCOPE_AGENT);
    u64 b = __hip_atomic_load(q + 1, __ATOMIC_RELAXED, __HIP_MEMORY_SCOPE_AGENT);
    float4 r;
    ((u64*)&r)[0] = a;
    ((u64*)&r)[1] = b;
    return r;
}

// Two-level tree grid barrier (R11): 8 per-XCD group lines (128 B apart,
// 32 serialized arrivals each, parallel across lines) + 1 root line (8
// arrivals; all spinners read ONLY the root). Replaces the single-line
// counter (256 serialized same-line RMWs ~ 13-20 us/step). Monotonic
// counters -> replay-safe given host zeroing. Leading __syncthreads drains
// each wave's vmcnt so all h atomic-stores are globally visible at arrival.
__device__ __forceinline__ void tree_barrier(unsigned* grp, unsigned* root,
                                             int xcd, int t, int tid) {
    __syncthreads();
    if (tid == 0) {
        unsigned old = __hip_atomic_fetch_add(&grp[xcd * 32], 1u,
                           __ATOMIC_RELAXED, __HIP_MEMORY_SCOPE_AGENT);
        if (old + 1u == 32u * (unsigned)(t + 1))
            __hip_atomic_fetch_add(root, 1u,
                __ATOMIC_RELAXED, __HIP_MEMORY_SCOPE_AGENT);
        const unsigned tgt = 8u * (unsigned)(t + 1);
        while (__hip_atomic_load(root, __ATOMIC_RELAXED,
                                 __HIP_MEMORY_SCOPE_AGENT) < tgt) {
            __builtin_amdgcn_s_sleep(2);
        }
    }
    __syncthreads();
}

__global__ void fillz(float* p, int n) {
    int i = blockIdx.x * blockDim.x + threadIdx.x;
    if (i < n) p[i] = 0.0f;
}

// fp32 [n] -> bf16 (RTNE) [n]
__global__ void round_w(const float* __restrict__ W, ushort_t* __restrict__ hi, int n) {
    int i = blockIdx.x * blockDim.x + threadIdx.x;
    if (i < n) hi[i] = bf16_rtne(W[i]);
}

// ---------------------------------------------------------------------------
// Persistent cooperative encoder, v9 = R8's verified kernel (best: 7755us
// total, 23.5us/step) with ONE change: tree barrier instead of single-line
// counter. R8/R9/R10 showed step time is invariant to FETCH volume, h-
// multicast volume, and occupancy -> the untested constant is the barrier's
// 256 serialized same-line RMWs. Tiling/protocol byte-for-byte R8:
// grid 256 x 512thr, wave=(gate g, K-half kh), acc[4][2], swizzled A LDS,
// B direct-to-reg dbuf, 2-term (h_hi+h_lo) x W_bf16, agent-atomic h.
// ---------------------------------------------------------------------------
__global__ __launch_bounds__(512, 2) void lstm_encoder_persistent(
    ushort_t* __restrict__ hhiA, ushort_t* __restrict__ hloA,   // buf0 (zeroed)
    ushort_t* __restrict__ hhiB, ushort_t* __restrict__ hloB,   // buf1
    float* __restrict__ h_fin,   // fp32 final h   (h_a)
    float* __restrict__ c_fin,   // fp32 final c   (c_st)
    const ushort_t* __restrict__ Whi1,
    const ushort_t* __restrict__ Whi2,
    const float* __restrict__ emb1, const float* __restrict__ emb2,
    const int* __restrict__ tok1, const int* __restrict__ len1,
    const int* __restrict__ tok2, const int* __restrict__ len2,
    unsigned* __restrict__ barGrp, unsigned* __restrict__ barRoot)
{
    // A regions: (grp*2 + parity)*16384; within region hi @+0, lo @+8192.
    __shared__ __align__(16) char smem[65536];
    float* Gx = (float*)smem;            // epilogue reuse: [4][64][36] fp32

    const int tid = threadIdx.x;
    const int w = tid >> 6;              // wave 0..7
    const int g = w & 3;                 // gate
    const int kh = w >> 2;               // K-half 0/1
    const int l = tid & 63;
    const int q = l >> 4;                // k-quad 0..3
    const int fr = l & 15;               // fragment row/col

    // XCD-aware decode: xcd = id&7; by in {xcd, xcd+8, xcd+16, xcd+24}
    const int id = blockIdx.x;
    const int xcd = id & 7;
    const int by = xcd + 8 * ((id >> 3) & 3);
    const int bx = id >> 5;
    const int fbase = bx * 64;
    const int n0 = by * 32;

    // --- A staging map ---
    const int sgrp = tid >> 8;
    const int u = tid & 255;
    const int ar = u >> 2;
    const int s0 = u & 3;
    const size_t a_goff = (size_t)(fbase + ar) * HH + s0 * 8 + sgrp * 512;
    const int sw0 = (s0 + ar) & 7;
    const int sw1 = ((s0 + 4) + ar) & 7;
    const int lds0 = ar * 8 + sw0;
    const int lds1 = ar * 8 + sw1;

    // --- B fragment offsets (W-base-independent) ---
    const size_t brow0 = ((size_t)(g * HH) + n0 + fr) * HH + q * 8 + kh * 512;
    const size_t brow1 = ((size_t)(g * HH) + n0 + 16 + fr) * HH + q * 8 + kh * 512;

    // --- epilogue map + persistent cell state ---
    const int rr = tid >> 3;
    const int c0 = (tid & 7) * 4;
    const int f = fbase + rr;
    const int gc = n0 + c0;
    const size_t gidx = (size_t)f * HH + gc;
    float4 creg = make_float4(0.f, 0.f, 0.f, 0.f);
    float4 hreg = make_float4(0.f, 0.f, 0.f, 0.f);

    // B double buffer (hi only); prefetch chunk0 of t=0
    short8 Bh[2][2][2];
    #pragma unroll
    for (int kk = 0; kk < 2; ++kk) {
        Bh[0][0][kk] = *(const short8*)(Whi1 + brow0 + kk * 32);
        Bh[0][1][kk] = *(const short8*)(Whi1 + brow1 + kk * 32);
    }

    for (int t = 0; t < 256; ++t) {
        const int tt = t & 127;
        const bool ph2 = t >= 128;
        const ushort_t* Wh = ph2 ? Whi2 : Whi1;
        const ushort_t* WhN = (t >= 127) ? Whi2 : Whi1;  // base for t+1
        const float* emb = ph2 ? emb2 : emb1;
        const int* tok = ph2 ? tok2 : tok1;
        const int* len = ph2 ? len2 : len1;
        const ushort_t* rhh = (t & 1) ? hhiB : hhiA;
        const ushort_t* rhl = (t & 1) ? hloB : hloA;
        ushort_t* whh = (t & 1) ? hhiA : hhiB;
        ushort_t* whl = (t & 1) ? hloA : hloB;

        // A chunk 0 -> LDS region (sgrp, 0)   (agent-scope bypass loads)
        {
            int4 h0 = ld_h16(rhh + a_goff);
            int4 h1 = ld_h16(rhh + a_goff + 32);
            int4 l0v = ld_h16(rhl + a_goff);
            int4 l1v = ld_h16(rhl + a_goff + 32);
            char* R0 = smem + sgrp * 32768;
            ((int4*)R0)[lds0] = h0;
            ((int4*)R0)[lds1] = h1;
            ((int4*)(R0 + 8192))[lds0] = l0v;
            ((int4*)(R0 + 8192))[lds1] = l1v;
        }
        __syncthreads();

        floatx4 acc[4][2];
        #pragma unroll
        for (int m = 0; m < 4; ++m)
            #pragma unroll
            for (int n = 0; n < 2; ++n) acc[m][n] = (floatx4)(0.0f);

        int4 pa_h0, pa_h1, pa_l0, pa_l1;
        #pragma unroll 2
        for (int i = 0; i < 8; ++i) {
            const int cur = i & 1, nxt = cur ^ 1;
            const char* AsH = smem + (kh * 2 + cur) * 16384;
            const char* AsL = AsH + 8192;

            // A prefetch for local chunk i+1
            if (i < 7) {
                const int k0 = (i + 1) * 64;
                pa_h0 = ld_h16(rhh + a_goff + k0);
                pa_h1 = ld_h16(rhh + a_goff + k0 + 32);
                pa_l0 = ld_h16(rhl + a_goff + k0);
                pa_l1 = ld_h16(rhl + a_goff + k0 + 32);
            }
            // B prefetch: chunks 1..7 of this step, or chunk0 of NEXT step at i==7
            {
                const ushort_t* Bsh = (i < 7) ? Wh : WhN;
                const int k0 = (i < 7) ? (i + 1) * 64 : 0;
                #pragma unroll
                for (int kk = 0; kk < 2; ++kk) {
                    Bh[nxt][0][kk] = *(const short8*)(Bsh + brow0 + k0 + kk * 32);
                    Bh[nxt][1][kk] = *(const short8*)(Bsh + brow1 + k0 + kk * 32);
                }
            }

            // compute local chunk i from region (kh, cur): 2-term
            //   g += h_hi @ W + h_lo @ W      (W = bf16-rounded)
            #pragma unroll
            for (int m = 0; m < 4; ++m) {
                const int r = m * 16 + fr;
                short8 ah0 = *(const short8*)(AsH + (r * 8 + ((0 + q + r) & 7)) * 16);
                short8 ah1 = *(const short8*)(AsH + (r * 8 + ((4 + q + r) & 7)) * 16);
                short8 al0 = *(const short8*)(AsL + (r * 8 + ((0 + q + r) & 7)) * 16);
                short8 al1 = *(const short8*)(AsL + (r * 8 + ((4 + q + r) & 7)) * 16);
                #pragma unroll
                for (int n = 0; n < 2; ++n) {
                    acc[m][n] = __builtin_amdgcn_mfma_f32_16x16x32_bf16(ah0, Bh[cur][n][0], acc[m][n], 0, 0, 0);
                    acc[m][n] = __builtin_amdgcn_mfma_f32_16x16x32_bf16(al0, Bh[cur][n][0], acc[m][n], 0, 0, 0);
                    acc[m][n] = __builtin_amdgcn_mfma_f32_16x16x32_bf16(ah1, Bh[cur][n][1], acc[m][n], 0, 0, 0);
                    acc[m][n] = __builtin_amdgcn_mfma_f32_16x16x32_bf16(al1, Bh[cur][n][1], acc[m][n], 0, 0, 0);
                }
            }

            if (i < 7) {
                char* DH = smem + (sgrp * 2 + nxt) * 16384;
                ((int4*)DH)[lds0] = pa_h0;
                ((int4*)DH)[lds1] = pa_h1;
                ((int4*)(DH + 8192))[lds0] = pa_l0;
                ((int4*)(DH + 8192))[lds1] = pa_l1;
            }
            __syncthreads();
        }

        // --- K-half reduce (C/D layout: col=fr, row=q*4+reg) ---
        if (kh == 1) {
            #pragma unroll
            for (int m = 0; m < 4; ++m)
                #pragma unroll
                for (int n = 0; n < 2; ++n)
                    #pragma unroll
                    for (int r = 0; r < 4; ++r)
                        Gx[(g * 64 + m * 16 + q * 4 + r) * 36 + n * 16 + fr] = acc[m][n][r];
        }
        __syncthreads();
        if (kh == 0) {
            #pragma unroll
            for (int m = 0; m < 4; ++m)
                #pragma unroll
                for (int n = 0; n < 2; ++n)
                    #pragma unroll
                    for (int r = 0; r < 4; ++r) {
                        const int idx = (g * 64 + m * 16 + q * 4 + r) * 36 + n * 16 + fr;
                        Gx[idx] += acc[m][n][r];
                    }
        }
        __syncthreads();

        // --- fused cell update; c and mask-h in registers ---
        const float* ib = emb + (size_t)tok[f * LL + tt] * 4096;
        const bool upd = tt < len[f];

        float4 gv[4];
        #pragma unroll
        for (int gg = 0; gg < 4; ++gg) {
            gv[gg] = *(const float4*)&Gx[(gg * 64 + rr) * 36 + c0];
            const float4 ibv = ld_f4_bypass(ib + gg * 1024 + gc);
            gv[gg].x += ibv.x; gv[gg].y += ibv.y; gv[gg].z += ibv.z; gv[gg].w += ibv.w;
        }

        unsigned short hb[4], lb[4];
        {
            const float* gi = (const float*)&gv[0];
            const float* gf = (const float*)&gv[1];
            const float* gn = (const float*)&gv[2];
            const float* go = (const float*)&gv[3];
            float* cr = (float*)&creg;
            float* hr = (float*)&hreg;
            #pragma unroll
            for (int j = 0; j < 4; ++j) {
                float cn = sigm(gf[j]) * cr[j] + sigm(gi[j]) * tanh_fast(gn[j]);
                float hn = sigm(go[j]) * tanh_fast(cn);
                if (upd) { cr[j] = cn; hr[j] = hn; }
                split_bf16(hr[j], hb[j], lb[j]);
            }
        }
        uint2 hp, lp;
        hp.x = (unsigned)hb[0] | ((unsigned)hb[1] << 16);
        hp.y = (unsigned)hb[2] | ((unsigned)hb[3] << 16);
        lp.x = (unsigned)lb[0] | ((unsigned)lb[1] << 16);
        lp.y = (unsigned)lb[2] | ((unsigned)lb[3] << 16);
        st_h8(whh + gidx, hp);
        st_h8(whl + gidx, lp);
        if (t == 255) {
            *(float4*)(h_fin + gidx) = hreg;
            *(float4*)(c_fin + gidx) = creg;
        }
        tree_barrier(barGrp, barRoot, xcd, t, tid);
    }
}

// ---------------------------------------------------------------------------
// bf16-split MFMA LSTM step (2-term) — used by the 16 decoder steps
// (initE = u_p, tokens/lengths = null). Unchanged from R8 (verified).
// ---------------------------------------------------------------------------
__global__ __launch_bounds__(512, 2) void lstm_step_mfma(
    const float* __restrict__ h_in,
    const ushort_t* __restrict__ hhi,
    const ushort_t* __restrict__ hlo,
    float* __restrict__ h_out,
    ushort_t* __restrict__ hhi_o,
    ushort_t* __restrict__ hlo_o,
    float* __restrict__ c_st,
    const ushort_t* __restrict__ Whi,
    const float* __restrict__ initE,
    const int* __restrict__ tokens,
    const int* __restrict__ lengths,
    int t)
{
    __shared__ __align__(16) char smem[65536];
    float* Gx = (float*)smem;

    const int tid = threadIdx.x;
    const int w = tid >> 6;
    const int g = w & 3;
    const int kh = w >> 2;
    const int l = tid & 63;
    const int q = l >> 4;
    const int fr = l & 15;

    const int id = blockIdx.x;
    const int by = (id & 7) + 8 * ((id >> 3) & 3);
    const int bx = id >> 5;
    const int fbase = bx * 64;
    const int n0 = by * 32;

    const int sgrp = tid >> 8;
    const int u = tid & 255;
    const int ar = u >> 2;
    const int s0 = u & 3;
    const size_t a_goff = (size_t)(fbase + ar) * HH + s0 * 8 + sgrp * 512;
    const int sw0 = (s0 + ar) & 7;
    const int sw1 = ((s0 + 4) + ar) & 7;
    const int lds0 = ar * 8 + sw0;
    const int lds1 = ar * 8 + sw1;

    const size_t brow0 = ((size_t)(g * HH) + n0 + fr) * HH + q * 8 + kh * 512;
    const size_t brow1 = ((size_t)(g * HH) + n0 + 16 + fr) * HH + q * 8 + kh * 512;

    floatx4 acc[4][2];
    #pragma unroll
    for (int m = 0; m < 4; ++m)
        #pragma unroll
        for (int n = 0; n < 2; ++n) acc[m][n] = (floatx4)(0.0f);

    int4 pa_h0 = *(const int4*)(hhi + a_goff);
    int4 pa_h1 = *(const int4*)(hhi + a_goff + 32);
    int4 pa_l0 = *(const int4*)(hlo + a_goff);
    int4 pa_l1 = *(const int4*)(hlo + a_goff + 32);

    short8 Bh[2][2][2];
    #pragma unroll
    for (int kk = 0; kk < 2; ++kk) {
        Bh[0][0][kk] = *(const short8*)(Whi + brow0 + kk * 32);
        Bh[0][1][kk] = *(const short8*)(Whi + brow1 + kk * 32);
    }

    {
        char* R0 = smem + sgrp * 32768;
        ((int4*)R0)[lds0] = pa_h0;
        ((int4*)R0)[lds1] = pa_h1;
        ((int4*)(R0 + 8192))[lds0] = pa_l0;
        ((int4*)(R0 + 8192))[lds1] = pa_l1;
    }
    __syncthreads();

    #pragma unroll 2
    for (int i = 0; i < 8; ++i) {
        const int cur = i & 1, nxt = cur ^ 1;
        const char* AsH = smem + (kh * 2 + cur) * 16384;
        const char* AsL = AsH + 8192;

        if (i < 7) {
            const int k0 = (i + 1) * 64;
            pa_h0 = *(const int4*)(hhi + a_goff + k0);
            pa_h1 = *(const int4*)(hhi + a_goff + k0 + 32);
            pa_l0 = *(const int4*)(hlo + a_goff + k0);
            pa_l1 = *(const int4*)(hlo + a_goff + k0 + 32);
            #pragma unroll
            for (int kk = 0; kk < 2; ++kk) {
                Bh[nxt][0][kk] = *(const short8*)(Whi + brow0 + k0 + kk * 32);
                Bh[nxt][1][kk] = *(const short8*)(Whi + brow1 + k0 + kk * 32);
            }
        }

        #pragma unroll
        for (int m = 0; m < 4; ++m) {
            const int r = m * 16 + fr;
            short8 ah0 = *(const short8*)(AsH + (r * 8 + ((0 + q + r) & 7)) * 16);
            short8 ah1 = *(const short8*)(AsH + (r * 8 + ((4 + q + r) & 7)) * 16);
            short8 al0 = *(const short8*)(AsL + (r * 8 + ((0 + q + r) & 7)) * 16);
            short8 al1 = *(const short8*)(AsL + (r * 8 + ((4 + q + r) & 7)) * 16);
            #pragma unroll
            for (int n = 0; n < 2; ++n) {
                acc[m][n] = __builtin_amdgcn_mfma_f32_16x16x32_bf16(ah0, Bh[cur][n][0], acc[m][n], 0, 0, 0);
                acc[m][n] = __builtin_amdgcn_mfma_f32_16x16x32_bf16(al0, Bh[cur][n][0], acc[m][n], 0, 0, 0);
                acc[m][n] = __builtin_amdgcn_mfma_f32_16x16x32_bf16(ah1, Bh[cur][n][1], acc[m][n], 0, 0, 0);
                acc[m][n] = __builtin_amdgcn_mfma_f32_16x16x32_bf16(al1, Bh[cur][n][1], acc[m][n], 0, 0, 0);
            }
        }

        if (i < 7) {
            char* DH = smem + (sgrp * 2 + nxt) * 16384;
            ((int4*)DH)[lds0] = pa_h0;
            ((int4*)DH)[lds1] = pa_h1;
            ((int4*)(DH + 8192))[lds0] = pa_l0;
            ((int4*)(DH + 8192))[lds1] = pa_l1;
        }
        __syncthreads();
    }

    if (kh == 1) {
        #pragma unroll
        for (int m = 0; m < 4; ++m)
            #pragma unroll
            for (int n = 0; n < 2; ++n)
                #pragma unroll
                for (int r = 0; r < 4; ++r)
                    Gx[(g * 64 + m * 16 + q * 4 + r) * 36 + n * 16 + fr] = acc[m][n][r];
    }
    __syncthreads();
    if (kh == 0) {
        #pragma unroll
        for (int m = 0; m < 4; ++m)
            #pragma unroll
            for (int n = 0; n < 2; ++n)
                #pragma unroll
                for (int r = 0; r < 4; ++r) {
                    const int idx = (g * 64 + m * 16 + q * 4 + r) * 36 + n * 16 + fr;
                    Gx[idx] += acc[m][n][r];
                }
    }
    __syncthreads();

    const int rr = tid >> 3;
    const int c0 = (tid & 7) * 4;
    const int f = fbase + rr;
    const int gc = n0 + c0;
    const size_t gidx = (size_t)f * HH + gc;
    const float* ib = tokens ? (initE + (size_t)tokens[f * LL + t] * 4096)
                             : (initE + (size_t)f * 4096);
    const bool upd = lengths ? (t < lengths[f]) : true;

    float4 gv[4];
    #pragma unroll
    for (int gg = 0; gg < 4; ++gg) {
        gv[gg] = *(const float4*)&Gx[(gg * 64 + rr) * 36 + c0];
        const float4 ibv = *(const float4*)(ib + gg * 1024 + gc);
        gv[gg].x += ibv.x; gv[gg].y += ibv.y; gv[gg].z += ibv.z; gv[gg].w += ibv.w;
    }
    const float4 coldv = *(const float4*)(c_st + gidx);
    const float4 holdv = *(const float4*)(h_in + gidx);

    float4 cw, hw;
    unsigned short hb[4], lb[4];
    {
        const float* gi = (const float*)&gv[0];
        const float* gf = (const float*)&gv[1];
        const float* gn = (const float*)&gv[2];
        const float* go = (const float*)&gv[3];
        const float* co = (const float*)&coldv;
        const float* ho = (const float*)&holdv;
        #pragma unroll
        for (int j = 0; j < 4; ++j) {
            float cn = sigm(gf[j]) * co[j] + sigm(gi[j]) * tanh_fast(gn[j]);
            float hn = sigm(go[j]) * tanh_fast(cn);
            float cv = upd ? cn : co[j];
            float hv = upd ? hn : ho[j];
            ((float*)&cw)[j] = cv;
            ((float*)&hw)[j] = hv;
            split_bf16(hv, hb[j], lb[j]);
        }
    }
    *(float4*)(c_st + gidx) = cw;
    *(float4*)(h_out + gidx) = hw;
    uint2 hp, lp;
    hp.x = (unsigned)hb[0] | ((unsigned)hb[1] << 16);
    hp.y = (unsigned)hb[2] | ((unsigned)hb[3] << 16);
    lp.x = (unsigned)lb[0] | ((unsigned)lb[1] << 16);
    lp.y = (unsigned)lb[2] | ((unsigned)lb[3] << 16);
    *(uint2*)(hhi_o + gidx) = hp;
    *(uint2*)(hlo_o + gidx) = lp;
}

// ---------------------------------------------------------------------------
// Generic fp32 C[M][N] = A[M][K] @ W[N][K]^T + bias[N]
// grid (M/32, N/64), block 256; per thread 4x2.
// ---------------------------------------------------------------------------
__global__ __launch_bounds__(256) void gemm_bias(
    const float* __restrict__ A, const float* __restrict__ W,
    const float* __restrict__ bias, float* __restrict__ C,
    int N, int K)
{
    __shared__ __align__(16) float As[16][32];
    __shared__ __align__(16) float Bs[16][64];
    const int tid = threadIdx.x;
    const int tm = tid & 7;
    const int tn = tid >> 3;
    const int m0 = blockIdx.x * 32, n0 = blockIdx.y * 64;
    const int am = tid >> 3;
    const int ak = (tid & 7) * 2;
    const int br = tid >> 2;
    const int bk = (tid & 3) * 4;
    const float* arow = A + (size_t)(m0 + am) * K;
    const float* brow = W + (size_t)(n0 + br) * K;
    float acc[4][2] = {};
    const int tm4 = tm * 4, tn2 = tn * 2;

    for (int k0 = 0; k0 < K; k0 += 16) {
        __syncthreads();
        float2 av = *(const float2*)(arow + k0 + ak);
        float4 bv = *(const float4*)(brow + k0 + bk);
        As[ak][am] = av.x; As[ak + 1][am] = av.y;
        Bs[bk][br] = bv.x; Bs[bk + 1][br] = bv.y;
        Bs[bk + 2][br] = bv.z; Bs[bk + 3][br] = bv.w;
        __syncthreads();
        #pragma unroll
        for (int k = 0; k < 16; ++k) {
            float4 a = *(const float4*)&As[k][tm4];
            float2 b = *(const float2*)&Bs[k][tn2];
            acc[0][0] += a.x * b.x; acc[0][1] += a.x * b.y;
            acc[1][0] += a.y * b.x; acc[1][1] += a.y * b.y;
            acc[2][0] += a.z * b.x; acc[2][1] += a.z * b.y;
            acc[3][0] += a.w * b.x; acc[3][1] += a.w * b.y;
        }
    }
    float b0 = bias[n0 + tn2], b1 = bias[n0 + tn2 + 1];
    #pragma unroll
    for (int mi = 0; mi < 4; ++mi) {
        float2 o;
        o.x = acc[mi][0] + b0;
        o.y = acc[mi][1] + b1;
        *(float2*)(C + (size_t)(m0 + tm4 + mi) * N + n0 + tn2) = o;
    }
}

// ---------------------------------------------------------------------------
// pooled[b][n] = tanh(max_e (h[4b+e] @ W_mp^T) + b_mp)   (tanh monotone)
// ---------------------------------------------------------------------------
__global__ __launch_bounds__(256) void mp_pool(
    const float* __restrict__ h, const float* __restrict__ Wmp,
    const float* __restrict__ bmp, float* __restrict__ pooled)
{
    __shared__ __align__(16) float As[16][32];
    __shared__ __align__(16) float Bs[16][64];
    const int tid = threadIdx.x;
    const int tm = tid & 7;
    const int tn = tid >> 3;
    const int m0 = blockIdx.x * 32, n0 = blockIdx.y * 64;
    const int am = tid >> 3;
    const int ak = (tid & 7) * 2;
    const int br = tid >> 2;
    const int bk = (tid & 3) * 4;
    const float* arow = h + (size_t)(m0 + am) * HH;
    const float* brow = Wmp + (size_t)(n0 + br) * HH;
    float acc[4][2] = {};
    const int tm4 = tm * 4, tn2 = tn * 2;

    for (int k0 = 0; k0 < HH; k0 += 16) {
        __syncthreads();
        float2 av = *(const float2*)(arow + k0 + ak);
        float4 bv = *(const float4*)(brow + k0 + bk);
        As[ak][am] = av.x; As[ak + 1][am] = av.y;
        Bs[bk][br] = bv.x; Bs[bk + 1][br] = bv.y;
        Bs[bk + 2][br] = bv.z; Bs[bk + 3][br] = bv.w;
        __syncthreads();
        #pragma unroll
        for (int k = 0; k < 16; ++k) {
            float4 a = *(const float4*)&As[k][tm4];
            float2 b = *(const float2*)&Bs[k][tn2];
            acc[0][0] += a.x * b.x; acc[0][1] += a.x * b.y;
            acc[1][0] += a.y * b.x; acc[1][1] += a.y * b.y;
            acc[2][0] += a.z * b.x; acc[2][1] += a.z * b.y;
            acc[3][0] += a.w * b.x; acc[3][1] += a.w * b.y;
        }
    }
    float mx0 = fmaxf(fmaxf(acc[0][0], acc[1][0]), fmaxf(acc[2][0], acc[3][0]));
    float mx1 = fmaxf(fmaxf(acc[0][1], acc[1][1]), fmaxf(acc[2][1], acc[3][1]));
    mx0 += bmp[n0 + tn2];
    mx1 += bmp[n0 + tn2 + 1];
    float2 o;
    o.x = tanh_fast(mx0);
    o.y = tanh_fast(mx1);
    const int bidx = (m0 >> 2) + tm;
    *(float2*)(pooled + (size_t)bidx * HH + n0 + tn2) = o;
}

extern "C" void kernel_launch(void* const* d_in, const int* in_sizes, int n_in,
                              void* d_out, int out_size, void* d_ws, size_t ws_size,
                              hipStream_t stream)
{
    const int*   tokens_in   = (const int*)d_in[0];
    const int*   lengths_in  = (const int*)d_in[1];
    const int*   tokens_out  = (const int*)d_in[2];
    const int*   lengths_out = (const int*)d_in[3];
    const float* embedding   = (const float*)d_in[4];
    const float* W_ih_in     = (const float*)d_in[5];
    const float* W_hh_in     = (const float*)d_in[6];
    const float* b_in        = (const float*)d_in[7];
    const float* W_ih_out    = (const float*)d_in[8];
    const float* W_hh_out    = (const float*)d_in[9];
    const float* b_out       = (const float*)d_in[10];
    const float* W_ih_p      = (const float*)d_in[11];
    const float* W_hh_p      = (const float*)d_in[12];
    const float* b_p         = (const float*)d_in[13];
    const float* W_mp        = (const float*)d_in[14];
    const float* b_mp        = (const float*)d_in[15];
    const float* W_sm        = (const float*)d_in[16];
    const float* b_sm        = (const float*)d_in[17];
    float* out = (float*)d_out;

    // workspace layout (float units); total ~18.5M floats = 74 MB
    float* ws = (float*)d_ws;
    float* h_a      = ws;                  // 524288
    float* h_b      = ws + 524288;         // 524288
    float* c_st     = ws + 1048576;        // 524288
    float* embW_in  = ws + 1572864;        // 524288
    float* embW_out = ws + 2097152;        // 524288
    float* u_p      = ws + 2621440;        // 2097152
    float* pooled   = ws + 4718592;        // 131072
    ushort_t* hhi_a = (ushort_t*)(ws + 4849664);   // 524288 bf16
    ushort_t* hlo_a = (ushort_t*)(ws + 5111808);
    ushort_t* hhi_b = (ushort_t*)(ws + 5373952);
    ushort_t* hlo_b = (ushort_t*)(ws + 5636096);
    ushort_t* Whi_in  = (ushort_t*)(ws + 5898240); // 4194304 bf16 each
    ushort_t* Whi_out = (ushort_t*)(ws + 10092544);
    ushort_t* Whi_p   = (ushort_t*)(ws + 14286848);
    // barrier state: group lines at u32 idx {0,32,...,224}; root at idx 1024
    unsigned* barGrp  = (unsigned*)u_p;
    unsigned* barRoot = (unsigned*)u_p + 1024;

    // zero h0's bf16 hi/lo (hhi_a/hlo_a adjacent) + all barrier state
    fillz<<<2048, 256, 0, stream>>>(ws + 4849664, 524288);
    fillz<<<8, 256, 0, stream>>>(u_p, 2048);

    // round the three recurrent weight matrices to bf16 (hi only; 2-term)
    round_w<<<16384, 256, 0, stream>>>(W_hh_in,  Whi_in,  4194304);
    round_w<<<16384, 256, 0, stream>>>(W_hh_out, Whi_out, 4194304);
    round_w<<<16384, 256, 0, stream>>>(W_hh_p,   Whi_p,   4194304);

    // embW = embedding @ W_ih^T + b  (x @ W_ih collapses to a gather)
    gemm_bias<<<dim3(4, 64), 256, 0, stream>>>(embedding, W_ih_in, b_in, embW_in, 4096, 128);
    gemm_bias<<<dim3(4, 64), 256, 0, stream>>>(embedding, W_ih_out, b_out, embW_out, 4096, 128);

    // --- persistent cooperative encoder: both 128-step phases, one launch ---
    {
        void* kargs[] = {
            (void*)&hhi_a, (void*)&hlo_a, (void*)&hhi_b, (void*)&hlo_b,
            (void*)&h_a, (void*)&c_st,
            (void*)&Whi_in, (void*)&Whi_out,
            (void*)&embW_in, (void*)&embW_out,
            (void*)&tokens_in, (void*)&lengths_in,
            (void*)&tokens_out, (void*)&lengths_out,
            (void*)&barGrp, (void*)&barRoot
        };
        hipLaunchCooperativeKernel((void*)lstm_encoder_persistent,
                                   dim3(256), dim3(512), kargs, 0, stream);
    }

    // decoder handoff: final h in h_a (fp32) + hhi_a/hlo_a (bf16), c in c_st
    float* hc = h_a;  ushort_t* hic = hhi_a;  ushort_t* loc = hlo_a;
    float* hn = h_b;  ushort_t* hin = hhi_b;  ushort_t* lon = hlo_b;

    // u_p = prev_h @ W_ih_p^T + b_p  (prev_h constant across all 16 steps)
    gemm_bias<<<dim3(16, 64), 256, 0, stream>>>(hc, W_ih_p, b_p, u_p, 4096, 1024);

    for (int t = 0; t < 16; ++t) {
        lstm_step_mfma<<<256, 512, 0, stream>>>(
            hc, hic, loc, hn, hin, lon, c_st, Whi_p, u_p,
            nullptr, nullptr, t);
        mp_pool<<<dim3(16, 16), 256, 0, stream>>>(hn, W_mp, b_mp, pooled);
        gemm_bias<<<dim3(4, 16), 256, 0, stream>>>(pooled, W_sm, b_sm,
                                                   out + (size_t)t * (BB * PP), 1024, 1024);
        float* tf = hc; hc = hn; hn = tf;
        ushort_t* th = hic; hic = hin; hin = th;
        ushort_t* tl = loc; loc = lon; lon = tl;
    }
}

// Round 13
// 6768.773 us; speedup vs baseline: 1.2679x; 1.0561x over previous
//
#include <hip/hip_runtime.h>

#define FF 512
#define HH 1024
#define LL 128
#define BB 128
#define PP 1024

typedef short short8 __attribute__((ext_vector_type(8)));
typedef float floatx4 __attribute__((ext_vector_type(4)));
typedef unsigned short ushort_t;
typedef unsigned long long u64;

__device__ __forceinline__ float sigm(float x) {
    return 1.0f / (1.0f + __expf(-x));
}
// overflow-safe tanh: exp(-2|x|) underflows to 0 for large |x| -> +-1
__device__ __forceinline__ float tanh_fast(float x) {
    float ax = fabsf(x);
    float e = __expf(-2.0f * ax);
    float r = (1.0f - e) / (1.0f + e);
    return copysignf(r, x);
}

__device__ __forceinline__ unsigned short bf16_rtne(float x) {
    unsigned int u = __float_as_uint(x);
    return (unsigned short)((u + 0x7FFFu + ((u >> 16) & 1u)) >> 16);
}
__device__ __forceinline__ void split_bf16(float x, unsigned short& hi, unsigned short& lo) {
    hi = bf16_rtne(x);
    float hf = __uint_as_float(((unsigned int)hi) << 16);
    lo = bf16_rtne(x - hf);
}

// --- agent-scope h exchange: coherent across XCDs (verified R3/R4/R8/R11) ---
__device__ __forceinline__ int4 ld_h16(const ushort_t* p) {
    u64* q = (u64*)p;
    u64 a = __hip_atomic_load(q,     __ATOMIC_RELAXED, __HIP_MEMORY_SCOPE_AGENT);
    u64 b = __hip_atomic_load(q + 1, __ATOMIC_RELAXED, __HIP_MEMORY_SCOPE_AGENT);
    return make_int4((int)(unsigned)(a & 0xffffffffull), (int)(unsigned)(a >> 32),
                     (int)(unsigned)(b & 0xffffffffull), (int)(unsigned)(b >> 32));
}
__device__ __forceinline__ void st_h8(ushort_t* p, uint2 v) {
    u64 x = ((u64)v.y << 32) | (u64)v.x;
    __hip_atomic_store((u64*)p, x, __ATOMIC_RELAXED, __HIP_MEMORY_SCOPE_AGENT);
}
__device__ __forceinline__ float4 ld_f4_bypass(const float* p) {
    u64* q = (u64*)p;
    u64 a = __hip_atomic_load(q,     __ATOMIC_RELAXED, __HIP_MEMORY_SCOPE_AGENT);
    u64 b = __hip_atomic_load(q + 1, __ATOMIC_RELAXED, __HIP_MEMORY_SCOPE_AGENT);
    float4 r;
    ((u64*)&r)[0] = a;
    ((u64*)&r)[1] = b;
    return r;
}

// Per-row-group barrier (R12): block (bx,by) only consumes h rows written by
// the 32 blocks sharing bx -> sync only those. 8 independent lines (128 B
// apart), 32 arrivals each, spin on OWN line (no root stage, groups
// decoupled). Monotonic counters -> replay-safe given host zeroing. Leading
// __syncthreads drains vmcnt so all h atomic-stores are visible at arrival.
__device__ __forceinline__ void group_barrier(unsigned* grp, int bx, int t, int tid) {
    __syncthreads();
    if (tid == 0) {
        unsigned* line = &grp[bx * 32];
        __hip_atomic_fetch_add(line, 1u, __ATOMIC_RELAXED, __HIP_MEMORY_SCOPE_AGENT);
        const unsigned tgt = 32u * (unsigned)(t + 1);
        while (__hip_atomic_load(line, __ATOMIC_RELAXED,
                                 __HIP_MEMORY_SCOPE_AGENT) < tgt) {
            __builtin_amdgcn_s_sleep(2);
        }
    }
    __syncthreads();
}

__global__ void fillz(float* p, int n) {
    int i = blockIdx.x * blockDim.x + threadIdx.x;
    if (i < n) p[i] = 0.0f;
}

// fp32 [n] -> bf16 (RTNE) [n]
__global__ void round_w(const float* __restrict__ W, ushort_t* __restrict__ hi, int n) {
    int i = blockIdx.x * blockDim.x + threadIdx.x;
    if (i < n) hi[i] = bf16_rtne(W[i]);
}

// ---------------------------------------------------------------------------
// Persistent cooperative encoder, v10 = R11 winner (21us/step) + two fixes
// for the residual latency chain:
// 1. DEPTH-4 A PREFETCH: chunks 0-3's agent loads issued back-to-back at
//    step start (MLP); chunk i+4 issued at iter i into a 4-deep rotating
//    register buffer (fully unrolled -> regs, not scratch). The old serial
//    8x(load->write) chain (~900cy each, depth-1) collapses to ~1 latency.
// 2. PER-BX GROUP BARRIER: replaces tree barrier (no root stage; 8
//    decoupled lines x 32 arrivals).
// Everything else byte-for-byte R11: grid 256 x 512thr, wave=(gate g,
// K-half kh), acc[4][2], swizzled A LDS, B direct-to-reg dbuf, 2-term
// (h_hi+h_lo) x W_bf16, agent-atomic h, same accumulation order.
// ---------------------------------------------------------------------------
__global__ __launch_bounds__(512, 2) void lstm_encoder_persistent(
    ushort_t* __restrict__ hhiA, ushort_t* __restrict__ hloA,   // buf0 (zeroed)
    ushort_t* __restrict__ hhiB, ushort_t* __restrict__ hloB,   // buf1
    float* __restrict__ h_fin,   // fp32 final h   (h_a)
    float* __restrict__ c_fin,   // fp32 final c   (c_st)
    const ushort_t* __restrict__ Whi1,
    const ushort_t* __restrict__ Whi2,
    const float* __restrict__ emb1, const float* __restrict__ emb2,
    const int* __restrict__ tok1, const int* __restrict__ len1,
    const int* __restrict__ tok2, const int* __restrict__ len2,
    unsigned* __restrict__ barGrp)
{
    // A regions: (grp*2 + parity)*16384; within region hi @+0, lo @+8192.
    __shared__ __align__(16) char smem[65536];
    float* Gx = (float*)smem;            // epilogue reuse: [4][64][36] fp32

    const int tid = threadIdx.x;
    const int w = tid >> 6;              // wave 0..7
    const int g = w & 3;                 // gate
    const int kh = w >> 2;               // K-half 0/1
    const int l = tid & 63;
    const int q = l >> 4;                // k-quad 0..3
    const int fr = l & 15;               // fragment row/col

    // XCD-aware decode: xcd = id&7; by in {xcd, xcd+8, xcd+16, xcd+24}
    const int id = blockIdx.x;
    const int by = (id & 7) + 8 * ((id >> 3) & 3);
    const int bx = id >> 5;              // row-group 0..7 (barrier group)
    const int fbase = bx * 64;
    const int n0 = by * 32;

    // --- A staging map ---
    const int sgrp = tid >> 8;
    const int u = tid & 255;
    const int ar = u >> 2;
    const int s0 = u & 3;
    const size_t a_goff = (size_t)(fbase + ar) * HH + s0 * 8 + sgrp * 512;
    const int sw0 = (s0 + ar) & 7;
    const int sw1 = ((s0 + 4) + ar) & 7;
    const int lds0 = ar * 8 + sw0;
    const int lds1 = ar * 8 + sw1;

    // --- B fragment offsets (W-base-independent) ---
    const size_t brow0 = ((size_t)(g * HH) + n0 + fr) * HH + q * 8 + kh * 512;
    const size_t brow1 = ((size_t)(g * HH) + n0 + 16 + fr) * HH + q * 8 + kh * 512;

    // --- epilogue map + persistent cell state ---
    const int rr = tid >> 3;
    const int c0 = (tid & 7) * 4;
    const int f = fbase + rr;
    const int gc = n0 + c0;
    const size_t gidx = (size_t)f * HH + gc;
    float4 creg = make_float4(0.f, 0.f, 0.f, 0.f);
    float4 hreg = make_float4(0.f, 0.f, 0.f, 0.f);

    // B double buffer (hi only); prefetch chunk0 of t=0
    short8 Bh[2][2][2];
    #pragma unroll
    for (int kk = 0; kk < 2; ++kk) {
        Bh[0][0][kk] = *(const short8*)(Whi1 + brow0 + kk * 32);
        Bh[0][1][kk] = *(const short8*)(Whi1 + brow1 + kk * 32);
    }

    for (int t = 0; t < 256; ++t) {
        const int tt = t & 127;
        const bool ph2 = t >= 128;
        const ushort_t* Wh = ph2 ? Whi2 : Whi1;
        const ushort_t* WhN = (t >= 127) ? Whi2 : Whi1;  // base for t+1
        const float* emb = ph2 ? emb2 : emb1;
        const int* tok = ph2 ? tok2 : tok1;
        const int* len = ph2 ? len2 : len1;
        const ushort_t* rhh = (t & 1) ? hhiB : hhiA;
        const ushort_t* rhl = (t & 1) ? hloB : hloA;
        ushort_t* whh = (t & 1) ? hhiA : hhiB;
        ushort_t* whl = (t & 1) ? hloA : hloB;

        // depth-4 rotating A-register pipeline: issue chunks 0..3 NOW (MLP)
        int4 ra_h0[4], ra_h1[4], ra_l0[4], ra_l1[4];
        #pragma unroll
        for (int i = 0; i < 4; ++i) {
            const int k0 = i * 64;
            ra_h0[i] = ld_h16(rhh + a_goff + k0);
            ra_h1[i] = ld_h16(rhh + a_goff + k0 + 32);
            ra_l0[i] = ld_h16(rhl + a_goff + k0);
            ra_l1[i] = ld_h16(rhl + a_goff + k0 + 32);
        }
        // chunk 0 -> LDS region (sgrp, 0)
        {
            char* R0 = smem + sgrp * 32768;
            ((int4*)R0)[lds0] = ra_h0[0];
            ((int4*)R0)[lds1] = ra_h1[0];
            ((int4*)(R0 + 8192))[lds0] = ra_l0[0];
            ((int4*)(R0 + 8192))[lds1] = ra_l1[0];
        }
        __syncthreads();

        floatx4 acc[4][2];
        #pragma unroll
        for (int m = 0; m < 4; ++m)
            #pragma unroll
            for (int n = 0; n < 2; ++n) acc[m][n] = (floatx4)(0.0f);

        #pragma unroll
        for (int i = 0; i < 8; ++i) {
            const int cur = i & 1, nxt = cur ^ 1;
            const char* AsH = smem + (kh * 2 + cur) * 16384;
            const char* AsL = AsH + 8192;

            // issue A load for chunk i+4 into rotating slot (i+4)&3 == i&3
            // (old chunk i value already committed to LDS at iter i-1)
            if (i + 4 < 8) {
                const int s = i & 3;
                const int k0 = (i + 4) * 64;
                ra_h0[s] = ld_h16(rhh + a_goff + k0);
                ra_h1[s] = ld_h16(rhh + a_goff + k0 + 32);
                ra_l0[s] = ld_h16(rhl + a_goff + k0);
                ra_l1[s] = ld_h16(rhl + a_goff + k0 + 32);
            }
            // B prefetch: chunks 1..7 of this step, or chunk0 of NEXT step at i==7
            {
                const ushort_t* Bsh = (i < 7) ? Wh : WhN;
                const int k0 = (i < 7) ? (i + 1) * 64 : 0;
                #pragma unroll
                for (int kk = 0; kk < 2; ++kk) {
                    Bh[nxt][0][kk] = *(const short8*)(Bsh + brow0 + k0 + kk * 32);
                    Bh[nxt][1][kk] = *(const short8*)(Bsh + brow1 + k0 + kk * 32);
                }
            }

            // compute local chunk i from region (kh, cur): 2-term
            //   g += h_hi @ W + h_lo @ W      (W = bf16-rounded)
            #pragma unroll
            for (int m = 0; m < 4; ++m) {
                const int r = m * 16 + fr;
                short8 ah0 = *(const short8*)(AsH + (r * 8 + ((0 + q + r) & 7)) * 16);
                short8 ah1 = *(const short8*)(AsH + (r * 8 + ((4 + q + r) & 7)) * 16);
                short8 al0 = *(const short8*)(AsL + (r * 8 + ((0 + q + r) & 7)) * 16);
                short8 al1 = *(const short8*)(AsL + (r * 8 + ((4 + q + r) & 7)) * 16);
                #pragma unroll
                for (int n = 0; n < 2; ++n) {
                    acc[m][n] = __builtin_amdgcn_mfma_f32_16x16x32_bf16(ah0, Bh[cur][n][0], acc[m][n], 0, 0, 0);
                    acc[m][n] = __builtin_amdgcn_mfma_f32_16x16x32_bf16(al0, Bh[cur][n][0], acc[m][n], 0, 0, 0);
                    acc[m][n] = __builtin_amdgcn_mfma_f32_16x16x32_bf16(ah1, Bh[cur][n][1], acc[m][n], 0, 0, 0);
                    acc[m][n] = __builtin_amdgcn_mfma_f32_16x16x32_bf16(al1, Bh[cur][n][1], acc[m][n], 0, 0, 0);
                }
            }

            // stage chunk i+1 (regs slot (i+1)&3, loaded >=4 iters ago ->
            // vmcnt wait ~0) into region (sgrp, nxt)
            if (i < 7) {
                const int s = (i + 1) & 3;
                char* DH = smem + (sgrp * 2 + nxt) * 16384;
                ((int4*)DH)[lds0] = ra_h0[s];
                ((int4*)DH)[lds1] = ra_h1[s];
                ((int4*)(DH + 8192))[lds0] = ra_l0[s];
                ((int4*)(DH + 8192))[lds1] = ra_l1[s];
            }
            __syncthreads();
        }

        // --- K-half reduce (C/D layout: col=fr, row=q*4+reg) ---
        if (kh == 1) {
            #pragma unroll
            for (int m = 0; m < 4; ++m)
                #pragma unroll
                for (int n = 0; n < 2; ++n)
                    #pragma unroll
                    for (int r = 0; r < 4; ++r)
                        Gx[(g * 64 + m * 16 + q * 4 + r) * 36 + n * 16 + fr] = acc[m][n][r];
        }
        __syncthreads();
        if (kh == 0) {
            #pragma unroll
            for (int m = 0; m < 4; ++m)
                #pragma unroll
                for (int n = 0; n < 2; ++n)
                    #pragma unroll
                    for (int r = 0; r < 4; ++r) {
                        const int idx = (g * 64 + m * 16 + q * 4 + r) * 36 + n * 16 + fr;
                        Gx[idx] += acc[m][n][r];
                    }
        }
        __syncthreads();

        // --- fused cell update; c and mask-h in registers ---
        const float* ib = emb + (size_t)tok[f * LL + tt] * 4096;
        const bool upd = tt < len[f];

        float4 gv[4];
        #pragma unroll
        for (int gg = 0; gg < 4; ++gg) {
            gv[gg] = *(const float4*)&Gx[(gg * 64 + rr) * 36 + c0];
            const float4 ibv = ld_f4_bypass(ib + gg * 1024 + gc);
            gv[gg].x += ibv.x; gv[gg].y += ibv.y; gv[gg].z += ibv.z; gv[gg].w += ibv.w;
        }

        unsigned short hb[4], lb[4];
        {
            const float* gi = (const float*)&gv[0];
            const float* gf = (const float*)&gv[1];
            const float* gn = (const float*)&gv[2];
            const float* go = (const float*)&gv[3];
            float* cr = (float*)&creg;
            float* hr = (float*)&hreg;
            #pragma unroll
            for (int j = 0; j < 4; ++j) {
                float cn = sigm(gf[j]) * cr[j] + sigm(gi[j]) * tanh_fast(gn[j]);
                float hn = sigm(go[j]) * tanh_fast(cn);
                if (upd) { cr[j] = cn; hr[j] = hn; }
                split_bf16(hr[j], hb[j], lb[j]);
            }
        }
        uint2 hp, lp;
        hp.x = (unsigned)hb[0] | ((unsigned)hb[1] << 16);
        hp.y = (unsigned)hb[2] | ((unsigned)hb[3] << 16);
        lp.x = (unsigned)lb[0] | ((unsigned)lb[1] << 16);
        lp.y = (unsigned)lb[2] | ((unsigned)lb[3] << 16);
        st_h8(whh + gidx, hp);
        st_h8(whl + gidx, lp);
        if (t == 255) {
            *(float4*)(h_fin + gidx) = hreg;
            *(float4*)(c_fin + gidx) = creg;
        }
        group_barrier(barGrp, bx, t, tid);
    }
}

// ---------------------------------------------------------------------------
// bf16-split MFMA LSTM step (2-term) — used by the 16 decoder steps
// (initE = u_p, tokens/lengths = null). Unchanged from R8/R11 (verified).
// ---------------------------------------------------------------------------
__global__ __launch_bounds__(512, 2) void lstm_step_mfma(
    const float* __restrict__ h_in,
    const ushort_t* __restrict__ hhi,
    const ushort_t* __restrict__ hlo,
    float* __restrict__ h_out,
    ushort_t* __restrict__ hhi_o,
    ushort_t* __restrict__ hlo_o,
    float* __restrict__ c_st,
    const ushort_t* __restrict__ Whi,
    const float* __restrict__ initE,
    const int* __restrict__ tokens,
    const int* __restrict__ lengths,
    int t)
{
    __shared__ __align__(16) char smem[65536];
    float* Gx = (float*)smem;

    const int tid = threadIdx.x;
    const int w = tid >> 6;
    const int g = w & 3;
    const int kh = w >> 2;
    const int l = tid & 63;
    const int q = l >> 4;
    const int fr = l & 15;

    const int id = blockIdx.x;
    const int by = (id & 7) + 8 * ((id >> 3) & 3);
    const int bx = id >> 5;
    const int fbase = bx * 64;
    const int n0 = by * 32;

    const int sgrp = tid >> 8;
    const int u = tid & 255;
    const int ar = u >> 2;
    const int s0 = u & 3;
    const size_t a_goff = (size_t)(fbase + ar) * HH + s0 * 8 + sgrp * 512;
    const int sw0 = (s0 + ar) & 7;
    const int sw1 = ((s0 + 4) + ar) & 7;
    const int lds0 = ar * 8 + sw0;
    const int lds1 = ar * 8 + sw1;

    const size_t brow0 = ((size_t)(g * HH) + n0 + fr) * HH + q * 8 + kh * 512;
    const size_t brow1 = ((size_t)(g * HH) + n0 + 16 + fr) * HH + q * 8 + kh * 512;

    floatx4 acc[4][2];
    #pragma unroll
    for (int m = 0; m < 4; ++m)
        #pragma unroll
        for (int n = 0; n < 2; ++n) acc[m][n] = (floatx4)(0.0f);

    int4 pa_h0 = *(const int4*)(hhi + a_goff);
    int4 pa_h1 = *(const int4*)(hhi + a_goff + 32);
    int4 pa_l0 = *(const int4*)(hlo + a_goff);
    int4 pa_l1 = *(const int4*)(hlo + a_goff + 32);

    short8 Bh[2][2][2];
    #pragma unroll
    for (int kk = 0; kk < 2; ++kk) {
        Bh[0][0][kk] = *(const short8*)(Whi + brow0 + kk * 32);
        Bh[0][1][kk] = *(const short8*)(Whi + brow1 + kk * 32);
    }

    {
        char* R0 = smem + sgrp * 32768;
        ((int4*)R0)[lds0] = pa_h0;
        ((int4*)R0)[lds1] = pa_h1;
        ((int4*)(R0 + 8192))[lds0] = pa_l0;
        ((int4*)(R0 + 8192))[lds1] = pa_l1;
    }
    __syncthreads();

    #pragma unroll 2
    for (int i = 0; i < 8; ++i) {
        const int cur = i & 1, nxt = cur ^ 1;
        const char* AsH = smem + (kh * 2 + cur) * 16384;
        const char* AsL = AsH + 8192;

        if (i < 7) {
            const int k0 = (i + 1) * 64;
            pa_h0 = *(const int4*)(hhi + a_goff + k0);
            pa_h1 = *(const int4*)(hhi + a_goff + k0 + 32);
            pa_l0 = *(const int4*)(hlo + a_goff + k0);
            pa_l1 = *(const int4*)(hlo + a_goff + k0 + 32);
            #pragma unroll
            for (int kk = 0; kk < 2; ++kk) {
                Bh[nxt][0][kk] = *(const short8*)(Whi + brow0 + k0 + kk * 32);
                Bh[nxt][1][kk] = *(const short8*)(Whi + brow1 + k0 + kk * 32);
            }
        }

        #pragma unroll
        for (int m = 0; m < 4; ++m) {
            const int r = m * 16 + fr;
            short8 ah0 = *(const short8*)(AsH + (r * 8 + ((0 + q + r) & 7)) * 16);
            short8 ah1 = *(const short8*)(AsH + (r * 8 + ((4 + q + r) & 7)) * 16);
            short8 al0 = *(const short8*)(AsL + (r * 8 + ((0 + q + r) & 7)) * 16);
            short8 al1 = *(const short8*)(AsL + (r * 8 + ((4 + q + r) & 7)) * 16);
            #pragma unroll
            for (int n = 0; n < 2; ++n) {
                acc[m][n] = __builtin_amdgcn_mfma_f32_16x16x32_bf16(ah0, Bh[cur][n][0], acc[m][n], 0, 0, 0);
                acc[m][n] = __builtin_amdgcn_mfma_f32_16x16x32_bf16(al0, Bh[cur][n][0], acc[m][n], 0, 0, 0);
                acc[m][n] = __builtin_amdgcn_mfma_f32_16x16x32_bf16(ah1, Bh[cur][n][1], acc[m][n], 0, 0, 0);
                acc[m][n] = __builtin_amdgcn_mfma_f32_16x16x32_bf16(al1, Bh[cur][n][1], acc[m][n], 0, 0, 0);
            }
        }

        if (i < 7) {
            char* DH = smem + (sgrp * 2 + nxt) * 16384;
            ((int4*)DH)[lds0] = pa_h0;
            ((int4*)DH)[lds1] = pa_h1;
            ((int4*)(DH + 8192))[lds0] = pa_l0;
            ((int4*)(DH + 8192))[lds1] = pa_l1;
        }
        __syncthreads();
    }

    if (kh == 1) {
        #pragma unroll
        for (int m = 0; m < 4; ++m)
            #pragma unroll
            for (int n = 0; n < 2; ++n)
                #pragma unroll
                for (int r = 0; r < 4; ++r)
                    Gx[(g * 64 + m * 16 + q * 4 + r) * 36 + n * 16 + fr] = acc[m][n][r];
    }
    __syncthreads();
    if (kh == 0) {
        #pragma unroll
        for (int m = 0; m < 4; ++m)
            #pragma unroll
            for (int n = 0; n < 2; ++n)
                #pragma unroll
                for (int r = 0; r < 4; ++r) {
                    const int idx = (g * 64 + m * 16 + q * 4 + r) * 36 + n * 16 + fr;
                    Gx[idx] += acc[m][n][r];
                }
    }
    __syncthreads();

    const int rr = tid >> 3;
    const int c0 = (tid & 7) * 4;
    const int f = fbase + rr;
    const int gc = n0 + c0;
    const size_t gidx = (size_t)f * HH + gc;
    const float* ib = tokens ? (initE + (size_t)tokens[f * LL + t] * 4096)
                             : (initE + (size_t)f * 4096);
    const bool upd = lengths ? (t < lengths[f]) : true;

    float4 gv[4];
    #pragma unroll
    for (int gg = 0; gg < 4; ++gg) {
        gv[gg] = *(const float4*)&Gx[(gg * 64 + rr) * 36 + c0];
        const float4 ibv = *(const float4*)(ib + gg * 1024 + gc);
        gv[gg].x += ibv.x; gv[gg].y += ibv.y; gv[gg].z += ibv.z; gv[gg].w += ibv.w;
    }
    const float4 coldv = *(const float4*)(c_st + gidx);
    const float4 holdv = *(const float4*)(h_in + gidx);

    float4 cw, hw;
    unsigned short hb[4], lb[4];
    {
        const float* gi = (const float*)&gv[0];
        const float* gf = (const float*)&gv[1];
        const float* gn = (const float*)&gv[2];
        const float* go = (const float*)&gv[3];
        const float* co = (const float*)&coldv;
        const float* ho = (const float*)&holdv;
        #pragma unroll
        for (int j = 0; j < 4; ++j) {
            float cn = sigm(gf[j]) * co[j] + sigm(gi[j]) * tanh_fast(gn[j]);
            float hn = sigm(go[j]) * tanh_fast(cn);
            float cv = upd ? cn : co[j];
            float hv = upd ? hn : ho[j];
            ((float*)&cw)[j] = cv;
            ((float*)&hw)[j] = hv;
            split_bf16(hv, hb[j], lb[j]);
        }
    }
    *(float4*)(c_st + gidx) = cw;
    *(float4*)(h_out + gidx) = hw;
    uint2 hp, lp;
    hp.x = (unsigned)hb[0] | ((unsigned)hb[1] << 16);
    hp.y = (unsigned)hb[2] | ((unsigned)hb[3] << 16);
    lp.x = (unsigned)lb[0] | ((unsigned)lb[1] << 16);
    lp.y = (unsigned)lb[2] | ((unsigned)lb[3] << 16);
    *(uint2*)(hhi_o + gidx) = hp;
    *(uint2*)(hlo_o + gidx) = lp;
}

// ---------------------------------------------------------------------------
// Generic fp32 C[M][N] = A[M][K] @ W[N][K]^T + bias[N]
// grid (M/32, N/64), block 256; per thread 4x2.
// ---------------------------------------------------------------------------
__global__ __launch_bounds__(256) void gemm_bias(
    const float* __restrict__ A, const float* __restrict__ W,
    const float* __restrict__ bias, float* __restrict__ C,
    int N, int K)
{
    __shared__ __align__(16) float As[16][32];
    __shared__ __align__(16) float Bs[16][64];
    const int tid = threadIdx.x;
    const int tm = tid & 7;
    const int tn = tid >> 3;
    const int m0 = blockIdx.x * 32, n0 = blockIdx.y * 64;
    const int am = tid >> 3;
    const int ak = (tid & 7) * 2;
    const int br = tid >> 2;
    const int bk = (tid & 3) * 4;
    const float* arow = A + (size_t)(m0 + am) * K;
    const float* brow = W + (size_t)(n0 + br) * K;
    float acc[4][2] = {};
    const int tm4 = tm * 4, tn2 = tn * 2;

    for (int k0 = 0; k0 < K; k0 += 16) {
        __syncthreads();
        float2 av = *(const float2*)(arow + k0 + ak);
        float4 bv = *(const float4*)(brow + k0 + bk);
        As[ak][am] = av.x; As[ak + 1][am] = av.y;
        Bs[bk][br] = bv.x; Bs[bk + 1][br] = bv.y;
        Bs[bk + 2][br] = bv.z; Bs[bk + 3][br] = bv.w;
        __syncthreads();
        #pragma unroll
        for (int k = 0; k < 16; ++k) {
            float4 a = *(const float4*)&As[k][tm4];
            float2 b = *(const float2*)&Bs[k][tn2];
            acc[0][0] += a.x * b.x; acc[0][1] += a.x * b.y;
            acc[1][0] += a.y * b.x; acc[1][1] += a.y * b.y;
            acc[2][0] += a.z * b.x; acc[2][1] += a.z * b.y;
            acc[3][0] += a.w * b.x; acc[3][1] += a.w * b.y;
        }
    }
    float b0 = bias[n0 + tn2], b1 = bias[n0 + tn2 + 1];
    #pragma unroll
    for (int mi = 0; mi < 4; ++mi) {
        float2 o;
        o.x = acc[mi][0] + b0;
        o.y = acc[mi][1] + b1;
        *(float2*)(C + (size_t)(m0 + tm4 + mi) * N + n0 + tn2) = o;
    }
}

// ---------------------------------------------------------------------------
// pooled[b][n] = tanh(max_e (h[4b+e] @ W_mp^T) + b_mp)   (tanh monotone)
// ---------------------------------------------------------------------------
__global__ __launch_bounds__(256) void mp_pool(
    const float* __restrict__ h, const float* __restrict__ Wmp,
    const float* __restrict__ bmp, float* __restrict__ pooled)
{
    __shared__ __align__(16) float As[16][32];
    __shared__ __align__(16) float Bs[16][64];
    const int tid = threadIdx.x;
    const int tm = tid & 7;
    const int tn = tid >> 3;
    const int m0 = blockIdx.x * 32, n0 = blockIdx.y * 64;
    const int am = tid >> 3;
    const int ak = (tid & 7) * 2;
    const int br = tid >> 2;
    const int bk = (tid & 3) * 4;
    const float* arow = h + (size_t)(m0 + am) * HH;
    const float* brow = Wmp + (size_t)(n0 + br) * HH;
    float acc[4][2] = {};
    const int tm4 = tm * 4, tn2 = tn * 2;

    for (int k0 = 0; k0 < HH; k0 += 16) {
        __syncthreads();
        float2 av = *(const float2*)(arow + k0 + ak);
        float4 bv = *(const float4*)(brow + k0 + bk);
        As[ak][am] = av.x; As[ak + 1][am] = av.y;
        Bs[bk][br] = bv.x; Bs[bk + 1][br] = bv.y;
        Bs[bk + 2][br] = bv.z; Bs[bk + 3][br] = bv.w;
        __syncthreads();
        #pragma unroll
        for (int k = 0; k < 16; ++k) {
            float4 a = *(const float4*)&As[k][tm4];
            float2 b = *(const float2*)&Bs[k][tn2];
            acc[0][0] += a.x * b.x; acc[0][1] += a.x * b.y;
            acc[1][0] += a.y * b.x; acc[1][1] += a.y * b.y;
            acc[2][0] += a.z * b.x; acc[2][1] += a.z * b.y;
            acc[3][0] += a.w * b.x; acc[3][1] += a.w * b.y;
        }
    }
    float mx0 = fmaxf(fmaxf(acc[0][0], acc[1][0]), fmaxf(acc[2][0], acc[3][0]));
    float mx1 = fmaxf(fmaxf(acc[0][1], acc[1][1]), fmaxf(acc[2][1], acc[3][1]));
    mx0 += bmp[n0 + tn2];
    mx1 += bmp[n0 + tn2 + 1];
    float2 o;
    o.x = tanh_fast(mx0);
    o.y = tanh_fast(mx1);
    const int bidx = (m0 >> 2) + tm;
    *(float2*)(pooled + (size_t)bidx * HH + n0 + tn2) = o;
}

extern "C" void kernel_launch(void* const* d_in, const int* in_sizes, int n_in,
                              void* d_out, int out_size, void* d_ws, size_t ws_size,
                              hipStream_t stream)
{
    const int*   tokens_in   = (const int*)d_in[0];
    const int*   lengths_in  = (const int*)d_in[1];
    const int*   tokens_out  = (const int*)d_in[2];
    const int*   lengths_out = (const int*)d_in[3];
    const float* embedding   = (const float*)d_in[4];
    const float* W_ih_in     = (const float*)d_in[5];
    const float* W_hh_in     = (const float*)d_in[6];
    const float* b_in        = (const float*)d_in[7];
    const float* W_ih_out    = (const float*)d_in[8];
    const float* W_hh_out    = (const float*)d_in[9];
    const float* b_out       = (const float*)d_in[10];
    const float* W_ih_p      = (const float*)d_in[11];
    const float* W_hh_p      = (const float*)d_in[12];
    const float* b_p         = (const float*)d_in[13];
    const float* W_mp        = (const float*)d_in[14];
    const float* b_mp        = (const float*)d_in[15];
    const float* W_sm        = (const float*)d_in[16];
    const float* b_sm        = (const float*)d_in[17];
    float* out = (float*)d_out;

    // workspace layout (float units); total ~18.5M floats = 74 MB
    float* ws = (float*)d_ws;
    float* h_a      = ws;                  // 524288
    float* h_b      = ws + 524288;         // 524288
    float* c_st     = ws + 1048576;        // 524288
    float* embW_in  = ws + 1572864;        // 524288
    float* embW_out = ws + 2097152;        // 524288
    float* u_p      = ws + 2621440;        // 2097152
    float* pooled   = ws + 4718592;        // 131072
    ushort_t* hhi_a = (ushort_t*)(ws + 4849664);   // 524288 bf16
    ushort_t* hlo_a = (ushort_t*)(ws + 5111808);
    ushort_t* hhi_b = (ushort_t*)(ws + 5373952);
    ushort_t* hlo_b = (ushort_t*)(ws + 5636096);
    ushort_t* Whi_in  = (ushort_t*)(ws + 5898240); // 4194304 bf16 each
    ushort_t* Whi_out = (ushort_t*)(ws + 10092544);
    ushort_t* Whi_p   = (ushort_t*)(ws + 14286848);
    // barrier state: 8 per-bx lines at u32 idx {0,32,...,224}
    unsigned* barGrp  = (unsigned*)u_p;

    // zero h0's bf16 hi/lo (hhi_a/hlo_a adjacent) + all barrier state
    fillz<<<2048, 256, 0, stream>>>(ws + 4849664, 524288);
    fillz<<<8, 256, 0, stream>>>(u_p, 2048);

    // round the three recurrent weight matrices to bf16 (hi only; 2-term)
    round_w<<<16384, 256, 0, stream>>>(W_hh_in,  Whi_in,  4194304);
    round_w<<<16384, 256, 0, stream>>>(W_hh_out, Whi_out, 4194304);
    round_w<<<16384, 256, 0, stream>>>(W_hh_p,   Whi_p,   4194304);

    // embW = embedding @ W_ih^T + b  (x @ W_ih collapses to a gather)
    gemm_bias<<<dim3(4, 64), 256, 0, stream>>>(embedding, W_ih_in, b_in, embW_in, 4096, 128);
    gemm_bias<<<dim3(4, 64), 256, 0, stream>>>(embedding, W_ih_out, b_out, embW_out, 4096, 128);

    // --- persistent cooperative encoder: both 128-step phases, one launch ---
    {
        void* kargs[] = {
            (void*)&hhi_a, (void*)&hlo_a, (void*)&hhi_b, (void*)&hlo_b,
            (void*)&h_a, (void*)&c_st,
            (void*)&Whi_in, (void*)&Whi_out,
            (void*)&embW_in, (void*)&embW_out,
            (void*)&tokens_in, (void*)&lengths_in,
            (void*)&tokens_out, (void*)&lengths_out,
            (void*)&barGrp
        };
        hipLaunchCooperativeKernel((void*)lstm_encoder_persistent,
                                   dim3(256), dim3(512), kargs, 0, stream);
    }

    // decoder handoff: final h in h_a (fp32) + hhi_a/hlo_a (bf16), c in c_st
    float* hc = h_a;  ushort_t* hic = hhi_a;  ushort_t* loc = hlo_a;
    float* hn = h_b;  ushort_t* hin = hhi_b;  ushort_t* lon = hlo_b;

    // u_p = prev_h @ W_ih_p^T + b_p  (prev_h constant across all 16 steps)
    gemm_bias<<<dim3(16, 64), 256, 0, stream>>>(hc, W_ih_p, b_p, u_p, 4096, 1024);

    for (int t = 0; t < 16; ++t) {
        lstm_step_mfma<<<256, 512, 0, stream>>>(
            hc, hic, loc, hn, hin, lon, c_st, Whi_p, u_p,
            nullptr, nullptr, t);
        mp_pool<<<dim3(16, 16), 256, 0, stream>>>(hn, W_mp, b_mp, pooled);
        gemm_bias<<<dim3(4, 16), 256, 0, stream>>>(pooled, W_sm, b_sm,
                                                   out + (size_t)t * (BB * PP), 1024, 1024);
        float* tf = hc; hc = hn; hn = tf;
        ushort_t* th = hic; hic = hin; hin = th;
        ushort_t* tl = loc; loc = lon; lon = tl;
    }
}

// Round 14
// 6225.861 us; speedup vs baseline: 1.3785x; 1.0872x over previous
//
#include <hip/hip_runtime.h>

#define FF 512
#define HH 1024
#define LL 128
#define BB 128
#define PP 1024

typedef short short8 __attribute__((ext_vector_type(8)));
typedef float floatx4 __attribute__((ext_vector_type(4)));
typedef unsigned short ushort_t;
typedef unsigned long long u64;

__device__ __forceinline__ float sigm(float x) {
    return 1.0f / (1.0f + __expf(-x));
}
// overflow-safe tanh: exp(-2|x|) underflows to 0 for large |x| -> +-1
__device__ __forceinline__ float tanh_fast(float x) {
    float ax = fabsf(x);
    float e = __expf(-2.0f * ax);
    float r = (1.0f - e) / (1.0f + e);
    return copysignf(r, x);
}

__device__ __forceinline__ unsigned short bf16_rtne(float x) {
    unsigned int u = __float_as_uint(x);
    return (unsigned short)((u + 0x7FFFu + ((u >> 16) & 1u)) >> 16);
}
__device__ __forceinline__ void split_bf16(float x, unsigned short& hi, unsigned short& lo) {
    hi = bf16_rtne(x);
    float hf = __uint_as_float(((unsigned int)hi) << 16);
    lo = bf16_rtne(x - hf);
}

// --- agent-scope h exchange: coherent across XCDs (verified R3/R4/R8/R11) ---
__device__ __forceinline__ int4 ld_h16(const ushort_t* p) {
    u64* q = (u64*)p;
    u64 a = __hip_atomic_load(q,     __ATOMIC_RELAXED, __HIP_MEMORY_SCOPE_AGENT);
    u64 b = __hip_atomic_load(q + 1, __ATOMIC_RELAXED, __HIP_MEMORY_SCOPE_AGENT);
    return make_int4((int)(unsigned)(a & 0xffffffffull), (int)(unsigned)(a >> 32),
                     (int)(unsigned)(b & 0xffffffffull), (int)(unsigned)(b >> 32));
}
__device__ __forceinline__ void st_h8(ushort_t* p, uint2 v) {
    u64 x = ((u64)v.y << 32) | (u64)v.x;
    __hip_atomic_store((u64*)p, x, __ATOMIC_RELAXED, __HIP_MEMORY_SCOPE_AGENT);
}
__device__ __forceinline__ float4 ld_f4_bypass(const float* p) {
    u64* q = (u64*)p;
    u64 a = __hip_atomic_load(q,     __ATOMIC_RELAXED, __HIP_MEMORY_SCOPE_AGENT);
    u64 b = __hip_atomic_load(q + 1, __ATOMIC_RELAXED, __HIP_MEMORY_SCOPE_AGENT);
    float4 r;
    ((u64*)&r)[0] = a;
    ((u64*)&r)[1] = b;
    return r;
}

// Per-row-group barrier (verified R12)
__device__ __forceinline__ void group_barrier(unsigned* grp, int bx, int t, int tid) {
    __syncthreads();
    if (tid == 0) {
        unsigned* line = &grp[bx * 32];
        __hip_atomic_fetch_add(line, 1u, __ATOMIC_RELAXED, __HIP_MEMORY_SCOPE_AGENT);
        const unsigned tgt = 32u * (unsigned)(t + 1);
        while (__hip_atomic_load(line, __ATOMIC_RELAXED,
                                 __HIP_MEMORY_SCOPE_AGENT) < tgt) {
            __builtin_amdgcn_s_sleep(2);
        }
    }
    __syncthreads();
}

__global__ void fillz(float* p, int n) {
    int i = blockIdx.x * blockDim.x + threadIdx.x;
    if (i < n) p[i] = 0.0f;
}

// fp32 [n] -> bf16 (RTNE) [n]
__global__ void round_w(const float* __restrict__ W, ushort_t* __restrict__ hi, int n) {
    int i = blockIdx.x * blockDim.x + threadIdx.x;
    if (i < n) hi[i] = bf16_rtne(W[i]);
}

// ---------------------------------------------------------------------------
// Persistent cooperative encoder, v10 (R12 winner, UNCHANGED): 20.0us/step.
// grid 256 x 512thr, wave=(gate g, K-half kh), acc[4][2], swizzled A LDS,
// depth-4 A prefetch, B direct-to-reg dbuf, 2-term (h_hi+h_lo) x W_bf16,
// agent-atomic h, per-bx group barrier.
// ---------------------------------------------------------------------------
__global__ __launch_bounds__(512, 2) void lstm_encoder_persistent(
    ushort_t* __restrict__ hhiA, ushort_t* __restrict__ hloA,   // buf0 (zeroed)
    ushort_t* __restrict__ hhiB, ushort_t* __restrict__ hloB,   // buf1
    float* __restrict__ h_fin,   // fp32 final h   (h_a)
    float* __restrict__ c_fin,   // fp32 final c   (c_st)
    const ushort_t* __restrict__ Whi1,
    const ushort_t* __restrict__ Whi2,
    const float* __restrict__ emb1, const float* __restrict__ emb2,
    const int* __restrict__ tok1, const int* __restrict__ len1,
    const int* __restrict__ tok2, const int* __restrict__ len2,
    unsigned* __restrict__ barGrp)
{
    __shared__ __align__(16) char smem[65536];
    float* Gx = (float*)smem;            // epilogue reuse: [4][64][36] fp32

    const int tid = threadIdx.x;
    const int w = tid >> 6;              // wave 0..7
    const int g = w & 3;                 // gate
    const int kh = w >> 2;               // K-half 0/1
    const int l = tid & 63;
    const int q = l >> 4;                // k-quad 0..3
    const int fr = l & 15;               // fragment row/col

    const int id = blockIdx.x;
    const int by = (id & 7) + 8 * ((id >> 3) & 3);
    const int bx = id >> 5;              // row-group 0..7 (barrier group)
    const int fbase = bx * 64;
    const int n0 = by * 32;

    const int sgrp = tid >> 8;
    const int u = tid & 255;
    const int ar = u >> 2;
    const int s0 = u & 3;
    const size_t a_goff = (size_t)(fbase + ar) * HH + s0 * 8 + sgrp * 512;
    const int sw0 = (s0 + ar) & 7;
    const int sw1 = ((s0 + 4) + ar) & 7;
    const int lds0 = ar * 8 + sw0;
    const int lds1 = ar * 8 + sw1;

    const size_t brow0 = ((size_t)(g * HH) + n0 + fr) * HH + q * 8 + kh * 512;
    const size_t brow1 = ((size_t)(g * HH) + n0 + 16 + fr) * HH + q * 8 + kh * 512;

    const int rr = tid >> 3;
    const int c0 = (tid & 7) * 4;
    const int f = fbase + rr;
    const int gc = n0 + c0;
    const size_t gidx = (size_t)f * HH + gc;
    float4 creg = make_float4(0.f, 0.f, 0.f, 0.f);
    float4 hreg = make_float4(0.f, 0.f, 0.f, 0.f);

    short8 Bh[2][2][2];
    #pragma unroll
    for (int kk = 0; kk < 2; ++kk) {
        Bh[0][0][kk] = *(const short8*)(Whi1 + brow0 + kk * 32);
        Bh[0][1][kk] = *(const short8*)(Whi1 + brow1 + kk * 32);
    }

    for (int t = 0; t < 256; ++t) {
        const int tt = t & 127;
        const bool ph2 = t >= 128;
        const ushort_t* Wh = ph2 ? Whi2 : Whi1;
        const ushort_t* WhN = (t >= 127) ? Whi2 : Whi1;
        const float* emb = ph2 ? emb2 : emb1;
        const int* tok = ph2 ? tok2 : tok1;
        const int* len = ph2 ? len2 : len1;
        const ushort_t* rhh = (t & 1) ? hhiB : hhiA;
        const ushort_t* rhl = (t & 1) ? hloB : hloA;
        ushort_t* whh = (t & 1) ? hhiA : hhiB;
        ushort_t* whl = (t & 1) ? hloA : hloB;

        // depth-4 rotating A-register pipeline: issue chunks 0..3 NOW (MLP)
        int4 ra_h0[4], ra_h1[4], ra_l0[4], ra_l1[4];
        #pragma unroll
        for (int i = 0; i < 4; ++i) {
            const int k0 = i * 64;
            ra_h0[i] = ld_h16(rhh + a_goff + k0);
            ra_h1[i] = ld_h16(rhh + a_goff + k0 + 32);
            ra_l0[i] = ld_h16(rhl + a_goff + k0);
            ra_l1[i] = ld_h16(rhl + a_goff + k0 + 32);
        }
        {
            char* R0 = smem + sgrp * 32768;
            ((int4*)R0)[lds0] = ra_h0[0];
            ((int4*)R0)[lds1] = ra_h1[0];
            ((int4*)(R0 + 8192))[lds0] = ra_l0[0];
            ((int4*)(R0 + 8192))[lds1] = ra_l1[0];
        }
        __syncthreads();

        floatx4 acc[4][2];
        #pragma unroll
        for (int m = 0; m < 4; ++m)
            #pragma unroll
            for (int n = 0; n < 2; ++n) acc[m][n] = (floatx4)(0.0f);

        #pragma unroll
        for (int i = 0; i < 8; ++i) {
            const int cur = i & 1, nxt = cur ^ 1;
            const char* AsH = smem + (kh * 2 + cur) * 16384;
            const char* AsL = AsH + 8192;

            if (i + 4 < 8) {
                const int s = i & 3;
                const int k0 = (i + 4) * 64;
                ra_h0[s] = ld_h16(rhh + a_goff + k0);
                ra_h1[s] = ld_h16(rhh + a_goff + k0 + 32);
                ra_l0[s] = ld_h16(rhl + a_goff + k0);
                ra_l1[s] = ld_h16(rhl + a_goff + k0 + 32);
            }
            {
                const ushort_t* Bsh = (i < 7) ? Wh : WhN;
                const int k0 = (i < 7) ? (i + 1) * 64 : 0;
                #pragma unroll
                for (int kk = 0; kk < 2; ++kk) {
                    Bh[nxt][0][kk] = *(const short8*)(Bsh + brow0 + k0 + kk * 32);
                    Bh[nxt][1][kk] = *(const short8*)(Bsh + brow1 + k0 + kk * 32);
                }
            }

            #pragma unroll
            for (int m = 0; m < 4; ++m) {
                const int r = m * 16 + fr;
                short8 ah0 = *(const short8*)(AsH + (r * 8 + ((0 + q + r) & 7)) * 16);
                short8 ah1 = *(const short8*)(AsH + (r * 8 + ((4 + q + r) & 7)) * 16);
                short8 al0 = *(const short8*)(AsL + (r * 8 + ((0 + q + r) & 7)) * 16);
                short8 al1 = *(const short8*)(AsL + (r * 8 + ((4 + q + r) & 7)) * 16);
                #pragma unroll
                for (int n = 0; n < 2; ++n) {
                    acc[m][n] = __builtin_amdgcn_mfma_f32_16x16x32_bf16(ah0, Bh[cur][n][0], acc[m][n], 0, 0, 0);
                    acc[m][n] = __builtin_amdgcn_mfma_f32_16x16x32_bf16(al0, Bh[cur][n][0], acc[m][n], 0, 0, 0);
                    acc[m][n] = __builtin_amdgcn_mfma_f32_16x16x32_bf16(ah1, Bh[cur][n][1], acc[m][n], 0, 0, 0);
                    acc[m][n] = __builtin_amdgcn_mfma_f32_16x16x32_bf16(al1, Bh[cur][n][1], acc[m][n], 0, 0, 0);
                }
            }

            if (i < 7) {
                const int s = (i + 1) & 3;
                char* DH = smem + (sgrp * 2 + nxt) * 16384;
                ((int4*)DH)[lds0] = ra_h0[s];
                ((int4*)DH)[lds1] = ra_h1[s];
                ((int4*)(DH + 8192))[lds0] = ra_l0[s];
                ((int4*)(DH + 8192))[lds1] = ra_l1[s];
            }
            __syncthreads();
        }

        if (kh == 1) {
            #pragma unroll
            for (int m = 0; m < 4; ++m)
                #pragma unroll
                for (int n = 0; n < 2; ++n)
                    #pragma unroll
                    for (int r = 0; r < 4; ++r)
                        Gx[(g * 64 + m * 16 + q * 4 + r) * 36 + n * 16 + fr] = acc[m][n][r];
        }
        __syncthreads();
        if (kh == 0) {
            #pragma unroll
            for (int m = 0; m < 4; ++m)
                #pragma unroll
                for (int n = 0; n < 2; ++n)
                    #pragma unroll
                    for (int r = 0; r < 4; ++r) {
                        const int idx = (g * 64 + m * 16 + q * 4 + r) * 36 + n * 16 + fr;
                        Gx[idx] += acc[m][n][r];
                    }
        }
        __syncthreads();

        const float* ib = emb + (size_t)tok[f * LL + tt] * 4096;
        const bool upd = tt < len[f];

        float4 gv[4];
        #pragma unroll
        for (int gg = 0; gg < 4; ++gg) {
            gv[gg] = *(const float4*)&Gx[(gg * 64 + rr) * 36 + c0];
            const float4 ibv = ld_f4_bypass(ib + gg * 1024 + gc);
            gv[gg].x += ibv.x; gv[gg].y += ibv.y; gv[gg].z += ibv.z; gv[gg].w += ibv.w;
        }

        unsigned short hb[4], lb[4];
        {
            const float* gi = (const float*)&gv[0];
            const float* gf = (const float*)&gv[1];
            const float* gn = (const float*)&gv[2];
            const float* go = (const float*)&gv[3];
            float* cr = (float*)&creg;
            float* hr = (float*)&hreg;
            #pragma unroll
            for (int j = 0; j < 4; ++j) {
                float cn = sigm(gf[j]) * cr[j] + sigm(gi[j]) * tanh_fast(gn[j]);
                float hn = sigm(go[j]) * tanh_fast(cn);
                if (upd) { cr[j] = cn; hr[j] = hn; }
                split_bf16(hr[j], hb[j], lb[j]);
            }
        }
        uint2 hp, lp;
        hp.x = (unsigned)hb[0] | ((unsigned)hb[1] << 16);
        hp.y = (unsigned)hb[2] | ((unsigned)hb[3] << 16);
        lp.x = (unsigned)lb[0] | ((unsigned)lb[1] << 16);
        lp.y = (unsigned)lb[2] | ((unsigned)lb[3] << 16);
        st_h8(whh + gidx, hp);
        st_h8(whl + gidx, lp);
        if (t == 255) {
            *(float4*)(h_fin + gidx) = hreg;
            *(float4*)(c_fin + gidx) = creg;
        }
        group_barrier(barGrp, bx, t, tid);
    }
}

// ---------------------------------------------------------------------------
// bf16-split MFMA LSTM step (2-term) — 16 decoder steps. Unchanged (verified).
// ---------------------------------------------------------------------------
__global__ __launch_bounds__(512, 2) void lstm_step_mfma(
    const float* __restrict__ h_in,
    const ushort_t* __restrict__ hhi,
    const ushort_t* __restrict__ hlo,
    float* __restrict__ h_out,
    ushort_t* __restrict__ hhi_o,
    ushort_t* __restrict__ hlo_o,
    float* __restrict__ c_st,
    const ushort_t* __restrict__ Whi,
    const float* __restrict__ initE,
    const int* __restrict__ tokens,
    const int* __restrict__ lengths,
    int t)
{
    __shared__ __align__(16) char smem[65536];
    float* Gx = (float*)smem;

    const int tid = threadIdx.x;
    const int w = tid >> 6;
    const int g = w & 3;
    const int kh = w >> 2;
    const int l = tid & 63;
    const int q = l >> 4;
    const int fr = l & 15;

    const int id = blockIdx.x;
    const int by = (id & 7) + 8 * ((id >> 3) & 3);
    const int bx = id >> 5;
    const int fbase = bx * 64;
    const int n0 = by * 32;

    const int sgrp = tid >> 8;
    const int u = tid & 255;
    const int ar = u >> 2;
    const int s0 = u & 3;
    const size_t a_goff = (size_t)(fbase + ar) * HH + s0 * 8 + sgrp * 512;
    const int sw0 = (s0 + ar) & 7;
    const int sw1 = ((s0 + 4) + ar) & 7;
    const int lds0 = ar * 8 + sw0;
    const int lds1 = ar * 8 + sw1;

    const size_t brow0 = ((size_t)(g * HH) + n0 + fr) * HH + q * 8 + kh * 512;
    const size_t brow1 = ((size_t)(g * HH) + n0 + 16 + fr) * HH + q * 8 + kh * 512;

    floatx4 acc[4][2];
    #pragma unroll
    for (int m = 0; m < 4; ++m)
        #pragma unroll
        for (int n = 0; n < 2; ++n) acc[m][n] = (floatx4)(0.0f);

    int4 pa_h0 = *(const int4*)(hhi + a_goff);
    int4 pa_h1 = *(const int4*)(hhi + a_goff + 32);
    int4 pa_l0 = *(const int4*)(hlo + a_goff);
    int4 pa_l1 = *(const int4*)(hlo + a_goff + 32);

    short8 Bh[2][2][2];
    #pragma unroll
    for (int kk = 0; kk < 2; ++kk) {
        Bh[0][0][kk] = *(const short8*)(Whi + brow0 + kk * 32);
        Bh[0][1][kk] = *(const short8*)(Whi + brow1 + kk * 32);
    }

    {
        char* R0 = smem + sgrp * 32768;
        ((int4*)R0)[lds0] = pa_h0;
        ((int4*)R0)[lds1] = pa_h1;
        ((int4*)(R0 + 8192))[lds0] = pa_l0;
        ((int4*)(R0 + 8192))[lds1] = pa_l1;
    }
    __syncthreads();

    #pragma unroll 2
    for (int i = 0; i < 8; ++i) {
        const int cur = i & 1, nxt = cur ^ 1;
        const char* AsH = smem + (kh * 2 + cur) * 16384;
        const char* AsL = AsH + 8192;

        if (i < 7) {
            const int k0 = (i + 1) * 64;
            pa_h0 = *(const int4*)(hhi + a_goff + k0);
            pa_h1 = *(const int4*)(hhi + a_goff + k0 + 32);
            pa_l0 = *(const int4*)(hlo + a_goff + k0);
            pa_l1 = *(const int4*)(hlo + a_goff + k0 + 32);
            #pragma unroll
            for (int kk = 0; kk < 2; ++kk) {
                Bh[nxt][0][kk] = *(const short8*)(Whi + brow0 + k0 + kk * 32);
                Bh[nxt][1][kk] = *(const short8*)(Whi + brow1 + k0 + kk * 32);
            }
        }

        #pragma unroll
        for (int m = 0; m < 4; ++m) {
            const int r = m * 16 + fr;
            short8 ah0 = *(const short8*)(AsH + (r * 8 + ((0 + q + r) & 7)) * 16);
            short8 ah1 = *(const short8*)(AsH + (r * 8 + ((4 + q + r) & 7)) * 16);
            short8 al0 = *(const short8*)(AsL + (r * 8 + ((0 + q + r) & 7)) * 16);
            short8 al1 = *(const short8*)(AsL + (r * 8 + ((4 + q + r) & 7)) * 16);
            #pragma unroll
            for (int n = 0; n < 2; ++n) {
                acc[m][n] = __builtin_amdgcn_mfma_f32_16x16x32_bf16(ah0, Bh[cur][n][0], acc[m][n], 0, 0, 0);
                acc[m][n] = __builtin_amdgcn_mfma_f32_16x16x32_bf16(al0, Bh[cur][n][0], acc[m][n], 0, 0, 0);
                acc[m][n] = __builtin_amdgcn_mfma_f32_16x16x32_bf16(ah1, Bh[cur][n][1], acc[m][n], 0, 0, 0);
                acc[m][n] = __builtin_amdgcn_mfma_f32_16x16x32_bf16(al1, Bh[cur][n][1], acc[m][n], 0, 0, 0);
            }
        }

        if (i < 7) {
            char* DH = smem + (sgrp * 2 + nxt) * 16384;
            ((int4*)DH)[lds0] = pa_h0;
            ((int4*)DH)[lds1] = pa_h1;
            ((int4*)(DH + 8192))[lds0] = pa_l0;
            ((int4*)(DH + 8192))[lds1] = pa_l1;
        }
        __syncthreads();
    }

    if (kh == 1) {
        #pragma unroll
        for (int m = 0; m < 4; ++m)
            #pragma unroll
            for (int n = 0; n < 2; ++n)
                #pragma unroll
                for (int r = 0; r < 4; ++r)
                    Gx[(g * 64 + m * 16 + q * 4 + r) * 36 + n * 16 + fr] = acc[m][n][r];
    }
    __syncthreads();
    if (kh == 0) {
        #pragma unroll
        for (int m = 0; m < 4; ++m)
            #pragma unroll
            for (int n = 0; n < 2; ++n)
                #pragma unroll
                for (int r = 0; r < 4; ++r) {
                    const int idx = (g * 64 + m * 16 + q * 4 + r) * 36 + n * 16 + fr;
                    Gx[idx] += acc[m][n][r];
                }
    }
    __syncthreads();

    const int rr = tid >> 3;
    const int c0 = (tid & 7) * 4;
    const int f = fbase + rr;
    const int gc = n0 + c0;
    const size_t gidx = (size_t)f * HH + gc;
    const float* ib = tokens ? (initE + (size_t)tokens[f * LL + t] * 4096)
                             : (initE + (size_t)f * 4096);
    const bool upd = lengths ? (t < lengths[f]) : true;

    float4 gv[4];
    #pragma unroll
    for (int gg = 0; gg < 4; ++gg) {
        gv[gg] = *(const float4*)&Gx[(gg * 64 + rr) * 36 + c0];
        const float4 ibv = *(const float4*)(ib + gg * 1024 + gc);
        gv[gg].x += ibv.x; gv[gg].y += ibv.y; gv[gg].z += ibv.z; gv[gg].w += ibv.w;
    }
    const float4 coldv = *(const float4*)(c_st + gidx);
    const float4 holdv = *(const float4*)(h_in + gidx);

    float4 cw, hw;
    unsigned short hb[4], lb[4];
    {
        const float* gi = (const float*)&gv[0];
        const float* gf = (const float*)&gv[1];
        const float* gn = (const float*)&gv[2];
        const float* go = (const float*)&gv[3];
        const float* co = (const float*)&coldv;
        const float* ho = (const float*)&holdv;
        #pragma unroll
        for (int j = 0; j < 4; ++j) {
            float cn = sigm(gf[j]) * co[j] + sigm(gi[j]) * tanh_fast(gn[j]);
            float hn = sigm(go[j]) * tanh_fast(cn);
            float cv = upd ? cn : co[j];
            float hv = upd ? hn : ho[j];
            ((float*)&cw)[j] = cv;
            ((float*)&hw)[j] = hv;
            split_bf16(hv, hb[j], lb[j]);
        }
    }
    *(float4*)(c_st + gidx) = cw;
    *(float4*)(h_out + gidx) = hw;
    uint2 hp, lp;
    hp.x = (unsigned)hb[0] | ((unsigned)hb[1] << 16);
    hp.y = (unsigned)hb[2] | ((unsigned)hb[3] << 16);
    lp.x = (unsigned)lb[0] | ((unsigned)lb[1] << 16);
    lp.y = (unsigned)lb[2] | ((unsigned)lb[3] << 16);
    *(uint2*)(hhi_o + gidx) = hp;
    *(uint2*)(hlo_o + gidx) = lp;
}

// ---------------------------------------------------------------------------
// MFMA 2-term GEMM: C[M][N] = (Ahi+Alo)[M][1024] @ Wb[N][1024]^T + bias[N].
// Block 64 rows x 128 cols; 8 waves = (col-group cg 0..3, K-half kh);
// grid (M/64, N/128). Same verified staging/loop/Gx-reduce as lstm_step.
// Used for u_p (N=4096). 
// ---------------------------------------------------------------------------
__global__ __launch_bounds__(512, 2) void mfma_gemm_bias(
    const ushort_t* __restrict__ Ahi, const ushort_t* __restrict__ Alo,
    const ushort_t* __restrict__ Wb, const float* __restrict__ bias,
    float* __restrict__ C, int N)
{
    __shared__ __align__(16) char smem[65536];
    float* Gx = (float*)smem;

    const int tid = threadIdx.x;
    const int w = tid >> 6;
    const int cg = w & 3;
    const int kh = w >> 2;
    const int l = tid & 63;
    const int q = l >> 4;
    const int fr = l & 15;

    const int fbase = blockIdx.x * 64;
    const int n0g = blockIdx.y * 128 + cg * 32;

    const int sgrp = tid >> 8;
    const int u = tid & 255;
    const int ar = u >> 2;
    const int s0 = u & 3;
    const size_t a_goff = (size_t)(fbase + ar) * HH + s0 * 8 + sgrp * 512;
    const int sw0 = (s0 + ar) & 7;
    const int sw1 = ((s0 + 4) + ar) & 7;
    const int lds0 = ar * 8 + sw0;
    const int lds1 = ar * 8 + sw1;

    const size_t brow0 = ((size_t)(n0g + fr)) * HH + q * 8 + kh * 512;
    const size_t brow1 = ((size_t)(n0g + 16 + fr)) * HH + q * 8 + kh * 512;

    floatx4 acc[4][2];
    #pragma unroll
    for (int m = 0; m < 4; ++m)
        #pragma unroll
        for (int n = 0; n < 2; ++n) acc[m][n] = (floatx4)(0.0f);

    int4 pa_h0 = *(const int4*)(Ahi + a_goff);
    int4 pa_h1 = *(const int4*)(Ahi + a_goff + 32);
    int4 pa_l0 = *(const int4*)(Alo + a_goff);
    int4 pa_l1 = *(const int4*)(Alo + a_goff + 32);

    short8 Bh[2][2][2];
    #pragma unroll
    for (int kk = 0; kk < 2; ++kk) {
        Bh[0][0][kk] = *(const short8*)(Wb + brow0 + kk * 32);
        Bh[0][1][kk] = *(const short8*)(Wb + brow1 + kk * 32);
    }

    {
        char* R0 = smem + sgrp * 32768;
        ((int4*)R0)[lds0] = pa_h0;
        ((int4*)R0)[lds1] = pa_h1;
        ((int4*)(R0 + 8192))[lds0] = pa_l0;
        ((int4*)(R0 + 8192))[lds1] = pa_l1;
    }
    __syncthreads();

    #pragma unroll 2
    for (int i = 0; i < 8; ++i) {
        const int cur = i & 1, nxt = cur ^ 1;
        const char* AsH = smem + (kh * 2 + cur) * 16384;
        const char* AsL = AsH + 8192;

        if (i < 7) {
            const int k0 = (i + 1) * 64;
            pa_h0 = *(const int4*)(Ahi + a_goff + k0);
            pa_h1 = *(const int4*)(Ahi + a_goff + k0 + 32);
            pa_l0 = *(const int4*)(Alo + a_goff + k0);
            pa_l1 = *(const int4*)(Alo + a_goff + k0 + 32);
            #pragma unroll
            for (int kk = 0; kk < 2; ++kk) {
                Bh[nxt][0][kk] = *(const short8*)(Wb + brow0 + k0 + kk * 32);
                Bh[nxt][1][kk] = *(const short8*)(Wb + brow1 + k0 + kk * 32);
            }
        }

        #pragma unroll
        for (int m = 0; m < 4; ++m) {
            const int r = m * 16 + fr;
            short8 ah0 = *(const short8*)(AsH + (r * 8 + ((0 + q + r) & 7)) * 16);
            short8 ah1 = *(const short8*)(AsH + (r * 8 + ((4 + q + r) & 7)) * 16);
            short8 al0 = *(const short8*)(AsL + (r * 8 + ((0 + q + r) & 7)) * 16);
            short8 al1 = *(const short8*)(AsL + (r * 8 + ((4 + q + r) & 7)) * 16);
            #pragma unroll
            for (int n = 0; n < 2; ++n) {
                acc[m][n] = __builtin_amdgcn_mfma_f32_16x16x32_bf16(ah0, Bh[cur][n][0], acc[m][n], 0, 0, 0);
                acc[m][n] = __builtin_amdgcn_mfma_f32_16x16x32_bf16(al0, Bh[cur][n][0], acc[m][n], 0, 0, 0);
                acc[m][n] = __builtin_amdgcn_mfma_f32_16x16x32_bf16(ah1, Bh[cur][n][1], acc[m][n], 0, 0, 0);
                acc[m][n] = __builtin_amdgcn_mfma_f32_16x16x32_bf16(al1, Bh[cur][n][1], acc[m][n], 0, 0, 0);
            }
        }

        if (i < 7) {
            char* DH = smem + (sgrp * 2 + nxt) * 16384;
            ((int4*)DH)[lds0] = pa_h0;
            ((int4*)DH)[lds1] = pa_h1;
            ((int4*)(DH + 8192))[lds0] = pa_l0;
            ((int4*)(DH + 8192))[lds1] = pa_l1;
        }
        __syncthreads();
    }

    if (kh == 1) {
        #pragma unroll
        for (int m = 0; m < 4; ++m)
            #pragma unroll
            for (int n = 0; n < 2; ++n)
                #pragma unroll
                for (int r = 0; r < 4; ++r)
                    Gx[(cg * 64 + m * 16 + q * 4 + r) * 36 + n * 16 + fr] = acc[m][n][r];
    }
    __syncthreads();
    if (kh == 0) {
        #pragma unroll
        for (int m = 0; m < 4; ++m)
            #pragma unroll
            for (int n = 0; n < 2; ++n)
                #pragma unroll
                for (int r = 0; r < 4; ++r) {
                    const int idx = (cg * 64 + m * 16 + q * 4 + r) * 36 + n * 16 + fr;
                    Gx[idx] += acc[m][n][r];
                }
    }
    __syncthreads();

    // epilogue: each thread writes 4x float4 (row rr, one quad per cg2)
    const int rr = tid >> 3;
    const int c8 = (tid & 7) * 4;
    #pragma unroll
    for (int cg2 = 0; cg2 < 4; ++cg2) {
        float4 v = *(const float4*)&Gx[(cg2 * 64 + rr) * 36 + c8];
        const int col = blockIdx.y * 128 + cg2 * 32 + c8;
        const float4 bv = *(const float4*)(bias + col);
        v.x += bv.x; v.y += bv.y; v.z += bv.z; v.w += bv.w;
        *(float4*)(C + (size_t)(fbase + rr) * N + col) = v;
    }
}

// ---------------------------------------------------------------------------
// MFMA 2-term mp_pool: pooled[b][n] = tanh(max_{e<4}((Ahi+Alo)[4b+e]@Wb^T)+bias)
// Same structure as mfma_gemm_bias; epilogue does the 4-row max + tanh.
// grid (512/64, 1024/128) = (8, 8).
// ---------------------------------------------------------------------------
__global__ __launch_bounds__(512, 2) void mp_pool_mfma(
    const ushort_t* __restrict__ Ahi, const ushort_t* __restrict__ Alo,
    const ushort_t* __restrict__ Wb, const float* __restrict__ bias,
    float* __restrict__ pooled)
{
    __shared__ __align__(16) char smem[65536];
    float* Gx = (float*)smem;

    const int tid = threadIdx.x;
    const int w = tid >> 6;
    const int cg = w & 3;
    const int kh = w >> 2;
    const int l = tid & 63;
    const int q = l >> 4;
    const int fr = l & 15;

    const int fbase = blockIdx.x * 64;
    const int n0g = blockIdx.y * 128 + cg * 32;

    const int sgrp = tid >> 8;
    const int u = tid & 255;
    const int ar = u >> 2;
    const int s0 = u & 3;
    const size_t a_goff = (size_t)(fbase + ar) * HH + s0 * 8 + sgrp * 512;
    const int sw0 = (s0 + ar) & 7;
    const int sw1 = ((s0 + 4) + ar) & 7;
    const int lds0 = ar * 8 + sw0;
    const int lds1 = ar * 8 + sw1;

    const size_t brow0 = ((size_t)(n0g + fr)) * HH + q * 8 + kh * 512;
    const size_t brow1 = ((size_t)(n0g + 16 + fr)) * HH + q * 8 + kh * 512;

    floatx4 acc[4][2];
    #pragma unroll
    for (int m = 0; m < 4; ++m)
        #pragma unroll
        for (int n = 0; n < 2; ++n) acc[m][n] = (floatx4)(0.0f);

    int4 pa_h0 = *(const int4*)(Ahi + a_goff);
    int4 pa_h1 = *(const int4*)(Ahi + a_goff + 32);
    int4 pa_l0 = *(const int4*)(Alo + a_goff);
    int4 pa_l1 = *(const int4*)(Alo + a_goff + 32);

    short8 Bh[2][2][2];
    #pragma unroll
    for (int kk = 0; kk < 2; ++kk) {
        Bh[0][0][kk] = *(const short8*)(Wb + brow0 + kk * 32);
        Bh[0][1][kk] = *(const short8*)(Wb + brow1 + kk * 32);
    }

    {
        char* R0 = smem + sgrp * 32768;
        ((int4*)R0)[lds0] = pa_h0;
        ((int4*)R0)[lds1] = pa_h1;
        ((int4*)(R0 + 8192))[lds0] = pa_l0;
        ((int4*)(R0 + 8192))[lds1] = pa_l1;
    }
    __syncthreads();

    #pragma unroll 2
    for (int i = 0; i < 8; ++i) {
        const int cur = i & 1, nxt = cur ^ 1;
        const char* AsH = smem + (kh * 2 + cur) * 16384;
        const char* AsL = AsH + 8192;

        if (i < 7) {
            const int k0 = (i + 1) * 64;
            pa_h0 = *(const int4*)(Ahi + a_goff + k0);
            pa_h1 = *(const int4*)(Ahi + a_goff + k0 + 32);
            pa_l0 = *(const int4*)(Alo + a_goff + k0);
            pa_l1 = *(const int4*)(Alo + a_goff + k0 + 32);
            #pragma unroll
            for (int kk = 0; kk < 2; ++kk) {
                Bh[nxt][0][kk] = *(const short8*)(Wb + brow0 + k0 + kk * 32);
                Bh[nxt][1][kk] = *(const short8*)(Wb + brow1 + k0 + kk * 32);
            }
        }

        #pragma unroll
        for (int m = 0; m < 4; ++m) {
            const int r = m * 16 + fr;
            short8 ah0 = *(const short8*)(AsH + (r * 8 + ((0 + q + r) & 7)) * 16);
            short8 ah1 = *(const short8*)(AsH + (r * 8 + ((4 + q + r) & 7)) * 16);
            short8 al0 = *(const short8*)(AsL + (r * 8 + ((0 + q + r) & 7)) * 16);
            short8 al1 = *(const short8*)(AsL + (r * 8 + ((4 + q + r) & 7)) * 16);
            #pragma unroll
            for (int n = 0; n < 2; ++n) {
                acc[m][n] = __builtin_amdgcn_mfma_f32_16x16x32_bf16(ah0, Bh[cur][n][0], acc[m][n], 0, 0, 0);
                acc[m][n] = __builtin_amdgcn_mfma_f32_16x16x32_bf16(al0, Bh[cur][n][0], acc[m][n], 0, 0, 0);
                acc[m][n] = __builtin_amdgcn_mfma_f32_16x16x32_bf16(ah1, Bh[cur][n][1], acc[m][n], 0, 0, 0);
                acc[m][n] = __builtin_amdgcn_mfma_f32_16x16x32_bf16(al1, Bh[cur][n][1], acc[m][n], 0, 0, 0);
            }
        }

        if (i < 7) {
            char* DH = smem + (sgrp * 2 + nxt) * 16384;
            ((int4*)DH)[lds0] = pa_h0;
            ((int4*)DH)[lds1] = pa_h1;
            ((int4*)(DH + 8192))[lds0] = pa_l0;
            ((int4*)(DH + 8192))[lds1] = pa_l1;
        }
        __syncthreads();
    }

    if (kh == 1) {
        #pragma unroll
        for (int m = 0; m < 4; ++m)
            #pragma unroll
            for (int n = 0; n < 2; ++n)
                #pragma unroll
                for (int r = 0; r < 4; ++r)
                    Gx[(cg * 64 + m * 16 + q * 4 + r) * 36 + n * 16 + fr] = acc[m][n][r];
    }
    __syncthreads();
    if (kh == 0) {
        #pragma unroll
        for (int m = 0; m < 4; ++m)
            #pragma unroll
            for (int n = 0; n < 2; ++n)
                #pragma unroll
                for (int r = 0; r < 4; ++r) {
                    const int idx = (cg * 64 + m * 16 + q * 4 + r) * 36 + n * 16 + fr;
                    Gx[idx] += acc[m][n][r];
                }
    }
    __syncthreads();

    // epilogue: 16 groups x 32 col-quads = 512 threads; max 4 rows, tanh
    const int gr = tid >> 5;             // example-group 0..15
    const int cq = tid & 31;             // col-quad 0..31
    const int cg2 = cq >> 3;
    const int c8 = (cq & 7) * 4;
    const int base = (cg2 * 64 + gr * 4) * 36 + c8;
    float4 v0 = *(const float4*)&Gx[base];
    float4 v1 = *(const float4*)&Gx[base + 36];
    float4 v2 = *(const float4*)&Gx[base + 72];
    float4 v3 = *(const float4*)&Gx[base + 108];
    const int col = blockIdx.y * 128 + cg2 * 32 + c8;
    const float4 bv = *(const float4*)(bias + col);
    float4 o;
    o.x = tanh_fast(fmaxf(fmaxf(v0.x, v1.x), fmaxf(v2.x, v3.x)) + bv.x);
    o.y = tanh_fast(fmaxf(fmaxf(v0.y, v1.y), fmaxf(v2.y, v3.y)) + bv.y);
    o.z = tanh_fast(fmaxf(fmaxf(v0.z, v1.z), fmaxf(v2.z, v3.z)) + bv.z);
    o.w = tanh_fast(fmaxf(fmaxf(v0.w, v1.w), fmaxf(v2.w, v3.w)) + bv.w);
    *(float4*)(pooled + (size_t)(blockIdx.x * 16 + gr) * HH + col) = o;
}

// ---------------------------------------------------------------------------
// Generic fp32 C[M][N] = A[M][K] @ W[N][K]^T + bias[N]  (embW, W_sm logits)
// ---------------------------------------------------------------------------
__global__ __launch_bounds__(256) void gemm_bias(
    const float* __restrict__ A, const float* __restrict__ W,
    const float* __restrict__ bias, float* __restrict__ C,
    int N, int K)
{
    __shared__ __align__(16) float As[16][32];
    __shared__ __align__(16) float Bs[16][64];
    const int tid = threadIdx.x;
    const int tm = tid & 7;
    const int tn = tid >> 3;
    const int m0 = blockIdx.x * 32, n0 = blockIdx.y * 64;
    const int am = tid >> 3;
    const int ak = (tid & 7) * 2;
    const int br = tid >> 2;
    const int bk = (tid & 3) * 4;
    const float* arow = A + (size_t)(m0 + am) * K;
    const float* brow = W + (size_t)(n0 + br) * K;
    float acc[4][2] = {};
    const int tm4 = tm * 4, tn2 = tn * 2;

    for (int k0 = 0; k0 < K; k0 += 16) {
        __syncthreads();
        float2 av = *(const float2*)(arow + k0 + ak);
        float4 bv = *(const float4*)(brow + k0 + bk);
        As[ak][am] = av.x; As[ak + 1][am] = av.y;
        Bs[bk][br] = bv.x; Bs[bk + 1][br] = bv.y;
        Bs[bk + 2][br] = bv.z; Bs[bk + 3][br] = bv.w;
        __syncthreads();
        #pragma unroll
        for (int k = 0; k < 16; ++k) {
            float4 a = *(const float4*)&As[k][tm4];
            float2 b = *(const float2*)&Bs[k][tn2];
            acc[0][0] += a.x * b.x; acc[0][1] += a.x * b.y;
            acc[1][0] += a.y * b.x; acc[1][1] += a.y * b.y;
            acc[2][0] += a.z * b.x; acc[2][1] += a.z * b.y;
            acc[3][0] += a.w * b.x; acc[3][1] += a.w * b.y;
        }
    }
    float b0 = bias[n0 + tn2], b1 = bias[n0 + tn2 + 1];
    #pragma unroll
    for (int mi = 0; mi < 4; ++mi) {
        float2 o;
        o.x = acc[mi][0] + b0;
        o.y = acc[mi][1] + b1;
        *(float2*)(C + (size_t)(m0 + tm4 + mi) * N + n0 + tn2) = o;
    }
}

extern "C" void kernel_launch(void* const* d_in, const int* in_sizes, int n_in,
                              void* d_out, int out_size, void* d_ws, size_t ws_size,
                              hipStream_t stream)
{
    const int*   tokens_in   = (const int*)d_in[0];
    const int*   lengths_in  = (const int*)d_in[1];
    const int*   tokens_out  = (const int*)d_in[2];
    const int*   lengths_out = (const int*)d_in[3];
    const float* embedding   = (const float*)d_in[4];
    const float* W_ih_in     = (const float*)d_in[5];
    const float* W_hh_in     = (const float*)d_in[6];
    const float* b_in        = (const float*)d_in[7];
    const float* W_ih_out    = (const float*)d_in[8];
    const float* W_hh_out    = (const float*)d_in[9];
    const float* b_out       = (const float*)d_in[10];
    const float* W_ih_p      = (const float*)d_in[11];
    const float* W_hh_p      = (const float*)d_in[12];
    const float* b_p         = (const float*)d_in[13];
    const float* W_mp        = (const float*)d_in[14];
    const float* b_mp        = (const float*)d_in[15];
    const float* W_sm        = (const float*)d_in[16];
    const float* b_sm        = (const float*)d_in[17];
    float* out = (float*)d_out;

    // workspace layout (float units); total ~18.5M floats = 74 MB
    float* ws = (float*)d_ws;
    float* h_a      = ws;                  // 524288
    float* h_b      = ws + 524288;         // 524288
    float* c_st     = ws + 1048576;        // 524288
    float* embW_in  = ws + 1572864;        // 524288
    float* embW_out = ws + 2097152;        // 524288
    float* u_p      = ws + 2621440;        // 2097152
    float* pooled   = ws + 4718592;        // 131072
    ushort_t* hhi_a = (ushort_t*)(ws + 4849664);   // 524288 bf16
    ushort_t* hlo_a = (ushort_t*)(ws + 5111808);
    ushort_t* hhi_b = (ushort_t*)(ws + 5373952);
    ushort_t* hlo_b = (ushort_t*)(ws + 5636096);
    ushort_t* Whi_in  = (ushort_t*)(ws + 5898240); // 4194304 bf16 each
    ushort_t* Wihp_hi = (ushort_t*)(ws + 7995392); // former Wlo_in slot
    ushort_t* Whi_out = (ushort_t*)(ws + 10092544);
    ushort_t* Wmp_hi  = (ushort_t*)(ws + 12189696); // former Wlo_out slot (1M used)
    ushort_t* Whi_p   = (ushort_t*)(ws + 14286848);
    // barrier state: 8 per-bx lines at u32 idx {0,32,...,224}
    unsigned* barGrp  = (unsigned*)u_p;

    // zero h0's bf16 hi/lo (hhi_a/hlo_a adjacent) + all barrier state
    fillz<<<2048, 256, 0, stream>>>(ws + 4849664, 524288);
    fillz<<<8, 256, 0, stream>>>(u_p, 2048);

    // round weight matrices to bf16 (2-term MFMA paths)
    round_w<<<16384, 256, 0, stream>>>(W_hh_in,  Whi_in,  4194304);
    round_w<<<16384, 256, 0, stream>>>(W_hh_out, Whi_out, 4194304);
    round_w<<<16384, 256, 0, stream>>>(W_hh_p,   Whi_p,   4194304);
    round_w<<<16384, 256, 0, stream>>>(W_ih_p,   Wihp_hi, 4194304);
    round_w<<<4096, 256, 0, stream>>>(W_mp,      Wmp_hi,  1048576);

    // embW = embedding @ W_ih^T + b  (x @ W_ih collapses to a gather)
    gemm_bias<<<dim3(4, 64), 256, 0, stream>>>(embedding, W_ih_in, b_in, embW_in, 4096, 128);
    gemm_bias<<<dim3(4, 64), 256, 0, stream>>>(embedding, W_ih_out, b_out, embW_out, 4096, 128);

    // --- persistent cooperative encoder: both 128-step phases, one launch ---
    {
        void* kargs[] = {
            (void*)&hhi_a, (void*)&hlo_a, (void*)&hhi_b, (void*)&hlo_b,
            (void*)&h_a, (void*)&c_st,
            (void*)&Whi_in, (void*)&Whi_out,
            (void*)&embW_in, (void*)&embW_out,
            (void*)&tokens_in, (void*)&lengths_in,
            (void*)&tokens_out, (void*)&lengths_out,
            (void*)&barGrp
        };
        hipLaunchCooperativeKernel((void*)lstm_encoder_persistent,
                                   dim3(256), dim3(512), kargs, 0, stream);
    }

    // decoder handoff: final h in h_a (fp32) + hhi_a/hlo_a (bf16), c in c_st
    float* hc = h_a;  ushort_t* hic = hhi_a;  ushort_t* loc = hlo_a;
    float* hn = h_b;  ushort_t* hin = hhi_b;  ushort_t* lon = hlo_b;

    // u_p = prev_h @ W_ih_p^T + b_p  (MFMA 2-term; prev_h bf16 in hic/loc)
    mfma_gemm_bias<<<dim3(8, 32), 512, 0, stream>>>(hic, loc, Wihp_hi, b_p, u_p, 4096);

    for (int t = 0; t < 16; ++t) {
        lstm_step_mfma<<<256, 512, 0, stream>>>(
            hc, hic, loc, hn, hin, lon, c_st, Whi_p, u_p,
            nullptr, nullptr, t);
        mp_pool_mfma<<<dim3(8, 8), 512, 0, stream>>>(hin, lon, Wmp_hi, b_mp, pooled);
        gemm_bias<<<dim3(4, 16), 256, 0, stream>>>(pooled, W_sm, b_sm,
                                                   out + (size_t)t * (BB * PP), 1024, 1024);
        float* tf = hc; hc = hn; hn = tf;
        ushort_t* th = hic; hic = hin; hin = th;
        ushort_t* tl = loc; loc = lon; lon = tl;
    }
}